// Round 13
// baseline (2428.973 us; speedup 1.0000x reference)
//
#include <hip/hip_runtime.h>
#include <hip/hip_bf16.h>
#include <math.h>

#define B_ 32
#define H_ 1024
#define V_ 32000
#define T_ 100
#define L_ 4
#define TB_ (T_*B_)      // 3200
#define N3H (3*H_)       // 3072
#define NBLK 224         // decode blocks: 32 (layer0) + 3*64 (layers 1-3)
#define L0BLK 32
#define NWRK 200         // logits worker blocks (co-scheduled with decode)
#define NCT  25          // TB_/128 col tiles
#define FSTRIDE 16       // flag padding: 16 uints = 64B per block
#define NVT (V_/128)     // 250 logits row tiles

typedef __attribute__((ext_vector_type(8))) short bf16x8;
typedef __attribute__((ext_vector_type(4))) float f32x4;
typedef __attribute__((ext_vector_type(4))) unsigned short u16x4;
typedef __attribute__((ext_vector_type(8))) unsigned short u16x8;

__device__ inline unsigned short f2bf(float f) {
    union { float f; unsigned u; } v; v.f = f;
    unsigned r = v.u + 0x7fff + ((v.u >> 16) & 1);   // RNE
    return (unsigned short)(r >> 16);
}
__device__ inline float bf2f(unsigned short u) {
    union { unsigned u; float f; } v; v.u = ((unsigned)u) << 16; return v.f;
}

// Device-coherent (L2-bypassing) 16B load: two relaxed agent-scope 8B atomics.
__device__ inline bf16x8 ld_h16(const unsigned short* p) {
    union { unsigned long long u[2]; bf16x8 v; } r;
    r.u[0] = __hip_atomic_load((const unsigned long long*)p,
                               __ATOMIC_RELAXED, __HIP_MEMORY_SCOPE_AGENT);
    r.u[1] = __hip_atomic_load((const unsigned long long*)(p + 4),
                               __ATOMIC_RELAXED, __HIP_MEMORY_SCOPE_AGENT);
    return r.v;
}
__device__ inline void st_h2(unsigned short* p, unsigned short v) {
    __hip_atomic_store(p, v, __ATOMIC_RELAXED, __HIP_MEMORY_SCOPE_AGENT);
}
__device__ inline unsigned ld_flag(const unsigned* p) {
    return __hip_atomic_load(p, __ATOMIC_RELAXED, __HIP_MEMORY_SCOPE_AGENT);
}

// async global->LDS 16B/lane copy (gfx950): LDS dest = uniform base + lane*16.
__device__ inline void gload_lds16(const unsigned short* g, unsigned short* lds)
{
    __builtin_amdgcn_global_load_lds(
        (const __attribute__((address_space(1))) void*)g,
        (__attribute__((address_space(3))) void*)lds, 16, 0, 0);
}

// ---------------------------------------------------------------------------
// fp32 -> bf16 contiguous convert (n4 = element count / 4)
// ---------------------------------------------------------------------------
__global__ __launch_bounds__(256) void convbf_kernel(
    const float* __restrict__ src, unsigned short* __restrict__ dst, int n4)
{
    for (int i = blockIdx.x * 256 + threadIdx.x; i < n4; i += gridDim.x * 256) {
        float4 v = ((const float4*)src)[i];
        u16x4 o; o.x = f2bf(v.x); o.y = f2bf(v.y); o.z = f2bf(v.z); o.w = f2bf(v.w);
        ((u16x4*)dst)[i] = o;
    }
}

// ---------------------------------------------------------------------------
// Ebf[t*B+b][h] = bf16(relu(emb[token(t,b)][h]))
// ---------------------------------------------------------------------------
__global__ __launch_bounds__(256) void embed_bf_kernel(
    const int* __restrict__ target, const float* __restrict__ emb,
    unsigned short* __restrict__ Ebf)
{
    int bid = blockIdx.x;                  // t*B+b
    int t = bid >> 5, b = bid & 31;
    int tok = (t == 0) ? 0 : target[b * T_ + (t - 1)];
    float4 v = ((const float4*)(emb + (size_t)tok * H_))[threadIdx.x];
    u16x4 o;
    o.x = f2bf(fmaxf(v.x, 0.f)); o.y = f2bf(fmaxf(v.y, 0.f));
    o.z = f2bf(fmaxf(v.z, 0.f)); o.w = f2bf(fmaxf(v.w, 0.f));
    ((u16x4*)(Ebf + (size_t)bid * H_))[threadIdx.x] = o;
}

// ---------------------------------------------------------------------------
// Attention collapse (step-invariant)
// ---------------------------------------------------------------------------
__global__ __launch_bounds__(256) void attn_pre_kernel(
    const float* __restrict__ enc_h, const float* __restrict__ l1_w,
    const float* __restrict__ l1_b, const float* __restrict__ l2_w,
    float* __restrict__ Cout, float* __restrict__ scores)
{
    __shared__ float L1h[96];
    __shared__ float sc[32];
    int tid = threadIdx.x, wv = tid >> 6, lane = tid & 63;
    for (int d = wv; d < 96; d += 4) {
        int b = d / 3, g = d - 3 * b;
        const float4* wp = (const float4*)(l1_w + (size_t)g * 2 * H_ + H_);
        const float4* ep = (const float4*)(enc_h + (size_t)b * H_);
        float s = 0.f;
        for (int q = lane; q < 256; q += 64) {
            float4 w4 = wp[q], e4 = ep[q];
            s += w4.x * e4.x + w4.y * e4.y + w4.z * e4.z + w4.w * e4.w;
        }
        for (int o = 32; o > 0; o >>= 1) s += __shfl_down(s, o);
        if (lane == 0) L1h[d] = s;
    }
    __syncthreads();
    if (tid < 32) {
        float cb = 0.f;
        for (int g = 0; g < 3; ++g) cb += l2_w[g] * (L1h[tid * 3 + g] + l1_b[g]);
        sc[tid] = cb;
    }
    __syncthreads();
    if (tid == 0) {
        float m = sc[0];
        for (int b = 1; b < 32; ++b) m = fmaxf(m, sc[b]);
        float s = 0.f;
        for (int b = 0; b < 32; ++b) { float e = expf(sc[b] - m); sc[b] = e; s += e; }
        float inv = 1.f / s;
        for (int b = 0; b < 32; ++b) { sc[b] *= inv; scores[b] = sc[b]; }
    }
    __syncthreads();
    float4 c = make_float4(0.f, 0.f, 0.f, 0.f);
    for (int b = 0; b < 32; ++b) {
        float4 e = ((const float4*)(enc_h + (size_t)b * H_))[tid];
        float ww = sc[b];
        c.x += ww * e.x; c.y += ww * e.y; c.z += ww * e.z; c.w += ww * e.w;
    }
    ((float4*)Cout)[tid] = c;
}

// ---------------------------------------------------------------------------
// wcC[n] = sum_k w_ih0[n][H+k] * C[k]
// ---------------------------------------------------------------------------
__global__ __launch_bounds__(256) void wcc_kernel(
    const float* __restrict__ w_ih0, const float* __restrict__ C,
    float* __restrict__ wcC)
{
    int row = blockIdx.x * 4 + (threadIdx.x >> 6);
    int lane = threadIdx.x & 63;
    const float4* wp = (const float4*)(w_ih0 + (size_t)row * 2 * H_ + H_);
    const float4* cp = (const float4*)C;
    float s = 0.f;
    for (int q = lane; q < 256; q += 64) {
        float4 w4 = wp[q], c4 = cp[q];
        s += w4.x * c4.x + w4.y * c4.y + w4.z * c4.z + w4.w * c4.w;
    }
    for (int o = 32; o > 0; o >>= 1) s += __shfl_down(s, o);
    if (lane == 0) wcC[row] = s;
}

// ---------------------------------------------------------------------------
// LDS-staged MFMA GEMM (256 threads), outMode 0: bf16 out[col*M+row].  (G0)
// ---------------------------------------------------------------------------
__global__ __launch_bounds__(256) void gemm_staged(
    const unsigned short* __restrict__ A, int lda,
    const unsigned short* __restrict__ Bb,
    const float* __restrict__ bias, int M,
    unsigned short* __restrict__ outp)
{
    __shared__ unsigned short Wt[128 * 64];
    __shared__ unsigned short Ht[128 * 64];

    const int tid = threadIdx.x, wv = tid >> 6, lane = tid & 63;
    const int rlo = lane & 15, khw = lane >> 4;
    const int rch = lane >> 3, slot = lane & 7;
    const int rowB = blockIdx.y * 128, colB = blockIdx.x * 128;
    const int wrow0 = rowB + (wv >> 1) * 64;
    const int wcol0 = colB + (wv & 1) * 64;
    const int rA = (wv >> 1) * 64, cA = (wv & 1) * 64;

    f32x4 acc[4][4];
    #pragma unroll
    for (int i = 0; i < 4; ++i)
        #pragma unroll
        for (int j = 0; j < 4; ++j) acc[i][j] = (f32x4){0.f, 0.f, 0.f, 0.f};

    for (int k0 = 0; k0 < H_; k0 += 64) {
        #pragma unroll
        for (int j = 0; j < 4; ++j) {
            int q = wv * 4 + j;
            int row = q * 8 + rch;
            int ss = slot ^ (row & 7);
            gload_lds16(A + (size_t)(rowB + row) * lda + k0 + ss * 8,
                        Wt + (size_t)q * 512);
            gload_lds16(Bb + (size_t)(colB + row) * H_ + k0 + ss * 8,
                        Ht + (size_t)q * 512);
        }
        __syncthreads();

        const char* WtB = (const char*)Wt;
        const char* HtB = (const char*)Ht;
        #pragma unroll
        for (int kk = 0; kk < 2; ++kk) {
            bf16x8 af[4], bfr[4];
            #pragma unroll
            for (int ri = 0; ri < 4; ++ri) {
                int row = rA + ri * 16 + rlo;
                int ch = (kk * 4 + khw) ^ (row & 7);
                af[ri] = *(const bf16x8*)(WtB + row * 128 + ch * 16);
            }
            #pragma unroll
            for (int ci = 0; ci < 4; ++ci) {
                int col = cA + ci * 16 + rlo;
                int ch = (kk * 4 + khw) ^ (col & 7);
                bfr[ci] = *(const bf16x8*)(HtB + col * 128 + ch * 16);
            }
            #pragma unroll
            for (int ri = 0; ri < 4; ++ri)
                #pragma unroll
                for (int ci = 0; ci < 4; ++ci)
                    acc[ri][ci] = __builtin_amdgcn_mfma_f32_16x16x32_bf16(
                        af[ri], bfr[ci], acc[ri][ci], 0, 0, 0);
        }
        __syncthreads();
    }

    int rowoff = (lane >> 4) * 4;
    #pragma unroll
    for (int ri = 0; ri < 4; ++ri) {
        int row = wrow0 + ri * 16 + rowoff;
        float4 bs = *(const float4*)(bias + row);
        #pragma unroll
        for (int ci = 0; ci < 4; ++ci) {
            int col = wcol0 + ci * 16 + rlo;
            u16x4 o;
            o.x = f2bf(acc[ri][ci][0] + bs.x); o.y = f2bf(acc[ri][ci][1] + bs.y);
            o.z = f2bf(acc[ri][ci][2] + bs.z); o.w = f2bf(acc[ri][ci][3] + bs.w);
            *(u16x4*)(outp + (size_t)col * M + row) = o;
        }
    }
}

// ---------------------------------------------------------------------------
// lse[col] = merge of NVT partials
// ---------------------------------------------------------------------------
__global__ __launch_bounds__(256) void lse_finish_kernel(
    const float2* __restrict__ P, float* __restrict__ lse)
{
    int col = blockIdx.x * 256 + threadIdx.x;
    if (col >= TB_) return;
    float M = -INFINITY, S = 0.f;
    for (int i = 0; i < NVT; ++i) {
        float2 p = P[(size_t)i * TB_ + col];
        float mm = fmaxf(M, p.x);
        S = S * __expf(M - mm) + p.y * __expf(p.x - mm);
        M = mm;
    }
    lse[col] = M + logf(S);
}

// ---------------------------------------------------------------------------
// dec_out[b][t][v] = bf2f(Lbf[col][v]) - lse[col],  col = t*32+b
// ---------------------------------------------------------------------------
__global__ __launch_bounds__(256) void subtract_kernel(
    const unsigned short* __restrict__ Lbf, const float* __restrict__ lse,
    float* __restrict__ dout)
{
    int col = blockIdx.x;
    int t = col >> 5, b = col & 31;
    float l = lse[col];
    const u16x8* L = (const u16x8*)(Lbf + (size_t)col * V_);
    float4* o = (float4*)(dout + ((size_t)b * T_ + t) * V_);
    for (int i = threadIdx.x; i < V_ / 8; i += 256) {
        u16x8 x = L[i];
        float4 v0, v1;
        v0.x = bf2f(x[0]) - l; v0.y = bf2f(x[1]) - l;
        v0.z = bf2f(x[2]) - l; v0.w = bf2f(x[3]) - l;
        v1.x = bf2f(x[4]) - l; v1.y = bf2f(x[5]) - l;
        v1.z = bf2f(x[6]) - l; v1.w = bf2f(x[7]) - l;
        o[i * 2] = v0; o[i * 2 + 1] = v1;
    }
}

// ---------------------------------------------------------------------------
// Fence-free direct-poll grid barrier (decode blocks only).
// ---------------------------------------------------------------------------
__device__ inline void grid_bar4(unsigned* flags, unsigned round)
{
    __syncthreads();
    if (threadIdx.x == 0) {
        asm volatile("s_waitcnt vmcnt(0)" ::: "memory");
        __hip_atomic_store(&flags[(size_t)blockIdx.x * FSTRIDE], round,
                           __ATOMIC_RELAXED, __HIP_MEMORY_SCOPE_AGENT);
    }
    int ok = (threadIdx.x >= NBLK) ? 1 : 0;
    while (true) {
        if (!ok)
            ok = (__hip_atomic_load(&flags[(size_t)threadIdx.x * FSTRIDE],
                                    __ATOMIC_RELAXED, __HIP_MEMORY_SCOPE_AGENT) >= round);
        if (__syncthreads_and(ok)) break;
        __builtin_amdgcn_s_sleep(2);
    }
}

// ---------------------------------------------------------------------------
// Combined persistent kernel:
//   bid < NBLK : pipelined GRU decode (round-6 structure, best measured)
//   bid >= NBLK: logits worker — waits on layer-3 flags, computes 128x128
//                logits tiles (bf16 + softmax partials) for finished cols.
// Shared-mem union: decode sacc (52KB) / worker Wt+Ht+smp (37KB).
// Workers read Hist via device-scope loads (per-XCD L2 may hold stale lines
// within one kernel); decode publishes Hist via device-scope stores.
// ---------------------------------------------------------------------------
__global__ __launch_bounds__(512, 2) void decode_kernel(
    const unsigned short* __restrict__ whh0_bf,   // [3H][H]
    const unsigned short* __restrict__ wih_bf,    // [3][3H][H]
    const unsigned short* __restrict__ whh_bf,    // [3][3H][H]
    const unsigned short* __restrict__ G0,        // [TB][3H] bf16
    const float* __restrict__ b_ih0, const float* __restrict__ b_hh0,
    const float* __restrict__ b_ih,  const float* __restrict__ b_hh,
    const float* __restrict__ enc_hidden,         // [L][B][H] fp32
    unsigned short* __restrict__ hbf,             // [2][L][B][H] bf16
    unsigned short* __restrict__ Hist,            // [TB][H] bf16
    float* __restrict__ hid_out,                  // d_out + B*T*V
    unsigned* __restrict__ flags,
    const unsigned short* __restrict__ outw,      // [V][H] bf16
    const float* __restrict__ out_b,              // [V]
    unsigned short* __restrict__ Lbf,             // [TB][V] bf16 logits
    float2* __restrict__ Ppart)                   // [NVT][TB]
{
    alignas(16) __shared__ char smem[52224];
    const int tid = threadIdx.x;
    const int bid = blockIdx.x;
    const int wv = tid >> 6, lane = tid & 63;
    const int rlo = lane & 15;
    const int rowoff = (lane >> 4) * 4;

    if (bid >= NBLK) {
        // ================= logits worker =================
        unsigned short* Wt = (unsigned short*)smem;                 // 16KB
        unsigned short* Ht = (unsigned short*)(smem + 16384);       // 16KB
        float2 (*smp)[4][16] = (float2 (*)[4][16])(smem + 32768);   // 4KB
        const int wkr = bid - NBLK;
        const int khw = lane >> 4;
        const int rch = lane >> 3, slot = lane & 7;
        const int rowq = wv >> 1, colh = wv & 1;
        const int rA = rowq * 32, cA = colh * 64;

        for (int ct = 0; ct < NCT; ++ct) {
            unsigned need = (unsigned)(4 * ct + 7);
            for (;;) {
                int ok = 1;
                if (tid < 64)
                    ok = (ld_flag(&flags[(size_t)(160 + tid) * FSTRIDE]) >= need);
                if (__syncthreads_and(ok)) break;
                __builtin_amdgcn_s_sleep(32);
            }
            const int colB = ct * 128;
            for (int rt = wkr; rt < NVT; rt += NWRK) {
                const int rowB = rt * 128;
                f32x4 acc[2][4];
                #pragma unroll
                for (int i = 0; i < 2; ++i)
                    #pragma unroll
                    for (int j = 0; j < 4; ++j) acc[i][j] = (f32x4){0.f, 0.f, 0.f, 0.f};

                for (int k0 = 0; k0 < H_; k0 += 64) {
                    #pragma unroll
                    for (int j = 0; j < 2; ++j) {
                        int q = wv * 2 + j;
                        int row = q * 8 + rch;
                        int ss = slot ^ (row & 7);
                        gload_lds16(outw + (size_t)(rowB + row) * H_ + k0 + ss * 8,
                                    Wt + (size_t)q * 512);
                        bf16x8 hv = ld_h16(Hist + (size_t)(colB + row) * H_ + k0 + ss * 8);
                        *(bf16x8*)(Ht + (size_t)row * 64 + slot * 8) = hv;
                    }
                    __syncthreads();
                    const char* WtB = (const char*)Wt;
                    const char* HtB = (const char*)Ht;
                    #pragma unroll
                    for (int kk = 0; kk < 2; ++kk) {
                        bf16x8 af[2], bfr[4];
                        #pragma unroll
                        for (int ri = 0; ri < 2; ++ri) {
                            int row = rA + ri * 16 + rlo;
                            int ch = (kk * 4 + khw) ^ (row & 7);
                            af[ri] = *(const bf16x8*)(WtB + row * 128 + ch * 16);
                        }
                        #pragma unroll
                        for (int ci = 0; ci < 4; ++ci) {
                            int col = cA + ci * 16 + rlo;
                            int ch = (kk * 4 + khw) ^ (col & 7);
                            bfr[ci] = *(const bf16x8*)(HtB + col * 128 + ch * 16);
                        }
                        #pragma unroll
                        for (int ri = 0; ri < 2; ++ri)
                            #pragma unroll
                            for (int ci = 0; ci < 4; ++ci)
                                acc[ri][ci] = __builtin_amdgcn_mfma_f32_16x16x32_bf16(
                                    af[ri], bfr[ci], acc[ri][ci], 0, 0, 0);
                    }
                    __syncthreads();
                }

                // epilogue: bf16 logits + per-col online (max,sumexp)
                float cm[4], cs[4];
                #pragma unroll
                for (int ci = 0; ci < 4; ++ci) { cm[ci] = -INFINITY; cs[ci] = 0.f; }
                #pragma unroll
                for (int ri = 0; ri < 2; ++ri) {
                    int row = rowB + rA + ri * 16 + rowoff;
                    float4 bs = *(const float4*)(out_b + row);
                    #pragma unroll
                    for (int ci = 0; ci < 4; ++ci) {
                        int col = colB + cA + ci * 16 + rlo;
                        float4 v;
                        v.x = acc[ri][ci][0] + bs.x; v.y = acc[ri][ci][1] + bs.y;
                        v.z = acc[ri][ci][2] + bs.z; v.w = acc[ri][ci][3] + bs.w;
                        u16x4 o; o.x = f2bf(v.x); o.y = f2bf(v.y);
                        o.z = f2bf(v.z); o.w = f2bf(v.w);
                        *(u16x4*)(Lbf + (size_t)col * V_ + row) = o;
                        float m4 = fmaxf(fmaxf(v.x, v.y), fmaxf(v.z, v.w));
                        if (m4 > cm[ci]) { cs[ci] *= __expf(cm[ci] - m4); cm[ci] = m4; }
                        cs[ci] += __expf(v.x - cm[ci]) + __expf(v.y - cm[ci])
                                + __expf(v.z - cm[ci]) + __expf(v.w - cm[ci]);
                    }
                }
                #pragma unroll
                for (int ci = 0; ci < 4; ++ci) {
                    #pragma unroll
                    for (int off = 16; off <= 32; off <<= 1) {
                        float om = __shfl_xor(cm[ci], off);
                        float os = __shfl_xor(cs[ci], off);
                        float mm = fmaxf(cm[ci], om);
                        cs[ci] = cs[ci] * __expf(cm[ci] - mm) + os * __expf(om - mm);
                        cm[ci] = mm;
                    }
                    if ((lane >> 4) == 0) smp[wv][ci][rlo] = make_float2(cm[ci], cs[ci]);
                }
                __syncthreads();
                if (tid < 128) {
                    int c2 = tid >> 6, ci = (tid >> 4) & 3, rl = tid & 15;
                    float2 a = smp[c2][ci][rl];
                    #pragma unroll
                    for (int q = 1; q < 4; ++q) {
                        float2 bq = smp[c2 + 2 * q][ci][rl];
                        float mm = fmaxf(a.x, bq.x);
                        a.y = a.y * __expf(a.x - mm) + bq.y * __expf(bq.x - mm);
                        a.x = mm;
                    }
                    int col = colB + c2 * 64 + ci * 16 + rl;
                    Ppart[(size_t)rt * TB_ + col] = a;
                }
                __syncthreads();
            }
        }
        return;
    }

    // ================= decode block (round-6 structure) =================
    float (*sacc)[4][16][34] = (float (*)[4][16][34])smem;  // [6][4][16][34]
    const int klane = (lane >> 4) * 8;

    int layer, f0;
    if (bid < L0BLK) { layer = 0; f0 = bid << 5; }
    else { int r = bid - L0BLK; layer = 1 + (r >> 6); f0 = (r & 63) << 4; }

    const unsigned short* Wih_l = (layer >= 1) ? wih_bf + (size_t)(layer - 1) * N3H * H_ : nullptr;
    const unsigned short* Whh_l = (layer >= 1) ? whh_bf + (size_t)(layer - 1) * N3H * H_ : whh0_bf;

    const int kc = wv & 3, srcgrp = wv >> 2;

    // ---- weight preload ----
    bf16x8 wreg[3][8];
    int rgv[3];
    #pragma unroll
    for (int i = 0; i < 3; ++i) {
        int rg = srcgrp * 3 + i;
        rgv[i] = rg;
        int wrow; const unsigned short* Wm;
        if (layer == 0)      { wrow = (rg >> 1) * H_ + f0 + (rg & 1) * 16; Wm = Whh_l; }
        else if (rg < 3)     { wrow = rg * H_ + f0;        Wm = Wih_l; }
        else                 { wrow = (rg - 3) * H_ + f0;  Wm = Whh_l; }
        const unsigned short* p = Wm + (size_t)(wrow + rlo) * H_ + kc * 256 + klane;
        #pragma unroll
        for (int s = 0; s < 8; ++s) wreg[i][s] = *(const bf16x8*)(p + s * 32);
    }

    // ---- bias + hold-state registers ----
    const float* bihp = (layer == 0) ? b_ih0 : b_ih + (size_t)(layer - 1) * N3H;
    const float* bhhp = (layer == 0) ? b_hh0 : b_hh + (size_t)(layer - 1) * N3H;
    int jj, eb0;
    float hold0, hold1 = 0.f;
    if (layer == 0) {
        jj = f0 + (tid & 31);
        eb0 = tid >> 5;
        hold0 = enc_hidden[(size_t)eb0 * H_ + jj];
        hold1 = enc_hidden[(size_t)(eb0 + 16) * H_ + jj];
    } else {
        jj = f0 + (tid & 15);               // coalesced epilogue stores
        eb0 = tid >> 4;
        hold0 = enc_hidden[(size_t)layer * B_ * H_ + (size_t)eb0 * H_ + jj];
    }
    const float bir = bihp[jj], biz = bihp[H_ + jj], bin_ = bihp[2 * H_ + jj];
    const float bhr = bhhp[jj], bhz = bhhp[H_ + jj], bhn = bhhp[2 * H_ + jj];

    const size_t BH = (size_t)B_ * H_;

    for (int c = 0; c < T_ + L_ - 1; ++c) {
        int t = c - layer;
        if (t >= 0 && t < T_) {
            int pw = t & 1, pr = pw ^ 1;
            const unsigned short* hown  = hbf + ((size_t)pr * L_ + layer) * BH;
            const unsigned short* hprev = (layer > 0)
                ? hbf + ((size_t)pw * L_ + (layer - 1)) * BH : nullptr;

            f32x4 acc[3][2];
            #pragma unroll
            for (int i = 0; i < 3; ++i) {
                acc[i][0] = (f32x4){0.f, 0.f, 0.f, 0.f};
                acc[i][1] = (f32x4){0.f, 0.f, 0.f, 0.f};
            }

            const unsigned short* hsrc = (layer == 0 || srcgrp == 1) ? hown : hprev;
            const unsigned short* hp = hsrc + (size_t)rlo * H_ + kc * 256 + klane;
            #pragma unroll
            for (int s = 0; s < 8; ++s) {
                bf16x8 b0 = ld_h16(hp + s * 32);
                bf16x8 b1 = ld_h16(hp + 16 * H_ + s * 32);
                #pragma unroll
                for (int i = 0; i < 3; ++i) {
                    acc[i][0] = __builtin_amdgcn_mfma_f32_16x16x32_bf16(wreg[i][s], b0, acc[i][0], 0, 0, 0);
                    acc[i][1] = __builtin_amdgcn_mfma_f32_16x16x32_bf16(wreg[i][s], b1, acc[i][1], 0, 0, 0);
                }
            }

            #pragma unroll
            for (int i = 0; i < 3; ++i)
                #pragma unroll
                for (int r = 0; r < 4; ++r) {
                    sacc[rgv[i]][kc][rowoff + r][rlo]      = acc[i][0][r];
                    sacc[rgv[i]][kc][rowoff + r][16 + rlo] = acc[i][1][r];
                }
            __syncthreads();

            if (layer > 0) {
                int f = tid & 15, b = tid >> 4;
                float ir = bir, iz = biz, in_ = bin_;
                float hr = bhr, hz = bhz, hn = bhn;
                #pragma unroll
                for (int k2 = 0; k2 < 4; ++k2) {
                    ir += sacc[0][k2][f][b]; iz += sacc[1][k2][f][b]; in_ += sacc[2][k2][f][b];
                    hr += sacc[3][k2][f][b]; hz += sacc[4][k2][f][b]; hn += sacc[5][k2][f][b];
                }
                float r = 1.f / (1.f + expf(-(ir + hr)));
                float z = 1.f / (1.f + expf(-(iz + hz)));
                float n = tanhf(in_ + r * hn);
                float hnew = (1.f - z) * n + z * hold0;
                hold0 = hnew;
                unsigned short hb16 = f2bf(hnew);
                st_h2(&hbf[((size_t)pw * L_ + layer) * BH + (size_t)b * H_ + jj], hb16);
                if (layer == L_ - 1) st_h2(&Hist[((size_t)t * B_ + b) * H_ + jj], hb16);
                if (t == T_ - 1) hid_out[(size_t)layer * BH + (size_t)b * H_ + jj] = hnew;
            } else {
                int fi = tid & 31;
                int rghalf = fi >> 4, fr = fi & 15;
                {
                    int b = eb0;
                    const unsigned short* g0p = G0 + ((size_t)t * B_ + b) * N3H;
                    float ir = bf2f(g0p[jj]) + bir;
                    float iz = bf2f(g0p[H_ + jj]) + biz;
                    float in_ = bf2f(g0p[2 * H_ + jj]) + bin_;
                    float hr = bhr, hz = bhz, hn = bhn;
                    #pragma unroll
                    for (int k2 = 0; k2 < 4; ++k2) {
                        hr += sacc[rghalf][k2][fr][b];
                        hz += sacc[2 + rghalf][k2][fr][b];
                        hn += sacc[4 + rghalf][k2][fr][b];
                    }
                    float r = 1.f / (1.f + expf(-(ir + hr)));
                    float z = 1.f / (1.f + expf(-(iz + hz)));
                    float n = tanhf(in_ + r * hn);
                    float hnew = (1.f - z) * n + z * hold0;
                    hold0 = hnew;
                    st_h2(&hbf[((size_t)pw * L_) * BH + (size_t)b * H_ + jj], f2bf(hnew));
                    if (t == T_ - 1) hid_out[(size_t)b * H_ + jj] = hnew;
                }
                {
                    int b = eb0 + 16;
                    const unsigned short* g0p = G0 + ((size_t)t * B_ + b) * N3H;
                    float ir = bf2f(g0p[jj]) + bir;
                    float iz = bf2f(g0p[H_ + jj]) + biz;
                    float in_ = bf2f(g0p[2 * H_ + jj]) + bin_;
                    float hr = bhr, hz = bhz, hn = bhn;
                    #pragma unroll
                    for (int k2 = 0; k2 < 4; ++k2) {
                        hr += sacc[rghalf][k2][fr][b];
                        hz += sacc[2 + rghalf][k2][fr][b];
                        hn += sacc[4 + rghalf][k2][fr][b];
                    }
                    float r = 1.f / (1.f + expf(-(ir + hr)));
                    float z = 1.f / (1.f + expf(-(iz + hz)));
                    float n = tanhf(in_ + r * hn);
                    float hnew = (1.f - z) * n + z * hold1;
                    hold1 = hnew;
                    st_h2(&hbf[((size_t)pw * L_) * BH + (size_t)b * H_ + jj], f2bf(hnew));
                    if (t == T_ - 1) hid_out[(size_t)b * H_ + jj] = hnew;
                }
            }
        }
        grid_bar4(flags, (unsigned)(c + 1));
    }
}

// ---------------------------------------------------------------------------
// Fallback in-place log_softmax + fp32 logits GEMM (workspace-short path)
// ---------------------------------------------------------------------------
__global__ __launch_bounds__(256) void logsoftmax_kernel(float* __restrict__ dout)
{
    __shared__ float red[256];
    float4* x4 = (float4*)(dout + (size_t)blockIdx.x * V_);
    const int N4 = V_ / 4;
    int tid = threadIdx.x;

    float m = -INFINITY, s = 0.f;
    for (int i = tid; i < N4; i += 256) {
        float4 v = x4[i];
        float m4 = fmaxf(fmaxf(v.x, v.y), fmaxf(v.z, v.w));
        if (m4 > m) { s *= expf(m - m4); m = m4; }
        s += expf(v.x - m) + expf(v.y - m) + expf(v.z - m) + expf(v.w - m);
    }
    red[tid] = m; __syncthreads();
    for (int o = 128; o > 0; o >>= 1) {
        if (tid < o) red[tid] = fmaxf(red[tid], red[tid + o]);
        __syncthreads();
    }
    float M = red[0]; __syncthreads();
    red[tid] = s * expf(m - M); __syncthreads();
    for (int o = 128; o > 0; o >>= 1) {
        if (tid < o) red[tid] += red[tid + o];
        __syncthreads();
    }
    float lse = M + logf(red[0]);

    for (int i = tid; i < N4; i += 256) {
        float4 v = x4[i];
        v.x -= lse; v.y -= lse; v.z -= lse; v.w -= lse;
        x4[i] = v;
    }
}

__global__ __launch_bounds__(256) void gemm_logits_f32(
    const unsigned short* __restrict__ A,
    const unsigned short* __restrict__ Bb,
    const float* __restrict__ bias, float* __restrict__ dout)
{
    __shared__ unsigned short Wt[128 * 64];
    __shared__ unsigned short Ht[128 * 64];
    const int tid = threadIdx.x, wv = tid >> 6, lane = tid & 63;
    const int rlo = lane & 15, khw = lane >> 4;
    const int rch = lane >> 3, slot = lane & 7;
    const int rowB = blockIdx.y * 128, colB = blockIdx.x * 128;
    const int wrow0 = rowB + (wv >> 1) * 64;
    const int wcol0 = colB + (wv & 1) * 64;
    const int rA = (wv >> 1) * 64, cA = (wv & 1) * 64;

    f32x4 acc[4][4];
    #pragma unroll
    for (int i = 0; i < 4; ++i)
        #pragma unroll
        for (int j = 0; j < 4; ++j) acc[i][j] = (f32x4){0.f, 0.f, 0.f, 0.f};

    for (int k0 = 0; k0 < H_; k0 += 64) {
        #pragma unroll
        for (int j = 0; j < 4; ++j) {
            int q = wv * 4 + j;
            int row = q * 8 + rch;
            int ss = slot ^ (row & 7);
            gload_lds16(A + (size_t)(rowB + row) * H_ + k0 + ss * 8, Wt + (size_t)q * 512);
            gload_lds16(Bb + (size_t)(colB + row) * H_ + k0 + ss * 8, Ht + (size_t)q * 512);
        }
        __syncthreads();
        const char* WtB = (const char*)Wt;
        const char* HtB = (const char*)Ht;
        #pragma unroll
        for (int kk = 0; kk < 2; ++kk) {
            bf16x8 af[4], bfr[4];
            #pragma unroll
            for (int ri = 0; ri < 4; ++ri) {
                int row = rA + ri * 16 + rlo;
                int ch = (kk * 4 + khw) ^ (row & 7);
                af[ri] = *(const bf16x8*)(WtB + row * 128 + ch * 16);
            }
            #pragma unroll
            for (int ci = 0; ci < 4; ++ci) {
                int col = cA + ci * 16 + rlo;
                int ch = (kk * 4 + khw) ^ (col & 7);
                bfr[ci] = *(const bf16x8*)(HtB + col * 128 + ch * 16);
            }
            #pragma unroll
            for (int ri = 0; ri < 4; ++ri)
                #pragma unroll
                for (int ci = 0; ci < 4; ++ci)
                    acc[ri][ci] = __builtin_amdgcn_mfma_f32_16x16x32_bf16(
                        af[ri], bfr[ci], acc[ri][ci], 0, 0, 0);
        }
        __syncthreads();
    }
    int rowoff = (lane >> 4) * 4;
    #pragma unroll
    for (int ri = 0; ri < 4; ++ri) {
        int row = wrow0 + ri * 16 + rowoff;
        float4 bs = *(const float4*)(bias + row);
        #pragma unroll
        for (int ci = 0; ci < 4; ++ci) {
            int col = wcol0 + ci * 16 + rlo;
            int tt = col >> 5, b = col & 31;
            float4 v;
            v.x = acc[ri][ci][0] + bs.x; v.y = acc[ri][ci][1] + bs.y;
            v.z = acc[ri][ci][2] + bs.z; v.w = acc[ri][ci][3] + bs.w;
            *(float4*)(dout + ((size_t)b * T_ + tt) * V_ + row) = v;
        }
    }
}

// ---------------------------------------------------------------------------
extern "C" void kernel_launch(void* const* d_in, const int* in_sizes, int n_in,
                              void* d_out, int out_size, void* d_ws, size_t ws_size,
                              hipStream_t stream)
{
    (void)in_sizes; (void)n_in; (void)out_size;

    const float* enc_hidden = (const float*)d_in[1];   // [L][B][H]; layer0 = enc_h
    const int*   target     = (const int*)  d_in[2];
    const float* emb        = (const float*)d_in[3];
    const float* w_ih0      = (const float*)d_in[4];   // [3H][2H]
    const float* w_hh0      = (const float*)d_in[5];   // [3H][H]
    const float* b_ih0      = (const float*)d_in[6];
    const float* b_hh0      = (const float*)d_in[7];
    const float* w_ih       = (const float*)d_in[8];   // [3][3H][H]
    const float* w_hh       = (const float*)d_in[9];
    const float* b_ih       = (const float*)d_in[10];
    const float* b_hh       = (const float*)d_in[11];
    const float* out_w      = (const float*)d_in[12];  // [V][H]
    const float* out_b      = (const float*)d_in[13];
    const float* l1_w       = (const float*)d_in[14];
    const float* l1_b       = (const float*)d_in[15];
    const float* l2_w       = (const float*)d_in[16];
    float* out = (float*)d_out;

    // --- workspace carve ---
    char* w = (char*)d_ws;
    auto alloc = [&](size_t bytes) -> char* {
        char* p = w; w += (bytes + 255) & ~(size_t)255; return p;
    };
    unsigned short* whh0_bf = (unsigned short*)alloc((size_t)N3H * H_ * 2);
    unsigned short* wih_bf  = (unsigned short*)alloc((size_t)3 * N3H * H_ * 2);
    unsigned short* whh_bf  = (unsigned short*)alloc((size_t)3 * N3H * H_ * 2);
    unsigned short* Ebf     = (unsigned short*)alloc((size_t)TB_ * H_ * 2);
    unsigned short* G0      = (unsigned short*)alloc((size_t)TB_ * N3H * 2);
    unsigned short* Hist    = (unsigned short*)alloc((size_t)TB_ * H_ * 2);
    unsigned short* hbf     = (unsigned short*)alloc((size_t)2 * L_ * B_ * H_ * 2);
    float*          Cbuf    = (float*)alloc(H_ * 4);
    float*          scores  = (float*)alloc(256);
    float*          wcC     = (float*)alloc(N3H * 4);
    unsigned*       flags   = (unsigned*)alloc((size_t)NBLK * FSTRIDE * 4);
    float2*         Ppart   = (float2*)alloc((size_t)NVT * TB_ * 8);      // 6.4 MB
    float*          lse     = (float*)alloc((size_t)TB_ * 4);

    size_t used = (size_t)(w - (char*)d_ws);
    unsigned short* wih0f_bf = nullptr;     // full w_ih0 in bf16 [3H][2H]
    if (used + (size_t)N3H * 2 * H_ * 2 + 256 <= ws_size)
        wih0f_bf = (unsigned short*)alloc((size_t)N3H * 2 * H_ * 2);
    used = (size_t)(w - (char*)d_ws);
    unsigned short* outw_bf = nullptr;
    if (used + (size_t)V_ * H_ * 2 + 256 <= ws_size)
        outw_bf = (unsigned short*)alloc((size_t)V_ * H_ * 2);
    used = (size_t)(w - (char*)d_ws);
    unsigned short* Lbf = nullptr;          // bf16 logits [TB][V] = 204.8 MB
    if (used + (size_t)TB_ * V_ * 2 + 256 <= ws_size)
        Lbf = (unsigned short*)alloc((size_t)TB_ * V_ * 2);

    const size_t LBH = (size_t)L_ * B_ * H_;
    const bool workers = (outw_bf != nullptr) && (Lbf != nullptr);

    hipMemsetAsync(flags, 0, (size_t)NBLK * FSTRIDE * 4, stream);

    // --- one-time precompute ---
    convbf_kernel<<<512, 256, 0, stream>>>(w_hh0, whh0_bf, N3H * H_ / 4);
    convbf_kernel<<<1024, 256, 0, stream>>>(w_ih, wih_bf, 3 * N3H * H_ / 4);
    convbf_kernel<<<1024, 256, 0, stream>>>(w_hh, whh_bf, 3 * N3H * H_ / 4);
    if (wih0f_bf)
        convbf_kernel<<<1024, 256, 0, stream>>>(w_ih0, wih0f_bf, N3H * 2 * H_ / 4);
    if (outw_bf)
        convbf_kernel<<<2048, 256, 0, stream>>>(out_w, outw_bf, V_ * H_ / 4);
    embed_bf_kernel<<<TB_, 256, 0, stream>>>(target, emb, Ebf);
    convbf_kernel<<<128, 256, 0, stream>>>(enc_hidden, hbf + LBH, (int)(LBH / 4));
    attn_pre_kernel<<<1, 256, 0, stream>>>(enc_hidden, l1_w, l1_b, l2_w, Cbuf, scores);
    wcc_kernel<<<N3H / 4, 256, 0, stream>>>(w_ih0, Cbuf, wcC);

    // G0 = W_E @ E (+ wcC bias)
    gemm_staged<<<dim3(TB_ / 128, N3H / 128), 256, 0, stream>>>(
        wih0f_bf, 2 * H_, Ebf, wcC, N3H, G0);

    // --- combined persistent decode + co-scheduled logits workers ---
    decode_kernel<<<workers ? NBLK + NWRK : NBLK, 512, 0, stream>>>(
        whh0_bf, wih_bf, whh_bf, G0, b_ih0, b_hh0, b_ih, b_hh,
        enc_hidden, hbf, Hist, out + (size_t)B_ * T_ * V_, flags,
        outw_bf, out_b, Lbf, Ppart);

    // --- softmax finish ---
    if (workers) {
        lse_finish_kernel<<<(TB_ + 255) / 256, 256, 0, stream>>>(Ppart, lse);
        subtract_kernel<<<TB_, 256, 0, stream>>>(Lbf, lse, out);
    } else if (outw_bf) {
        gemm_logits_f32<<<dim3(TB_ / 128, V_ / 128), 256, 0, stream>>>(
            outw_bf, Hist, out_b, out);
        logsoftmax_kernel<<<TB_, 256, 0, stream>>>(out);
    }

    hipMemcpyAsync(out + (size_t)B_ * T_ * V_ + LBH, scores, B_ * 4,
                   hipMemcpyDeviceToDevice, stream);
}

// Round 14
// 2181.662 us; speedup vs baseline: 1.1134x; 1.1134x over previous
//
#include <hip/hip_runtime.h>
#include <hip/hip_bf16.h>
#include <math.h>

#define B_ 32
#define H_ 1024
#define V_ 32000
#define T_ 100
#define L_ 4
#define TB_ (T_*B_)      // 3200
#define N3H (3*H_)       // 3072
#define NBLK 224         // decode grid: 32 (layer0) + 3*64 (layers 1-3)
#define L0BLK 32
#define FSTRIDE 16       // flag padding: 16 uints = 64B per block
#define NVT (V_/128)     // 250 logits row tiles
#define SACC_BYTES 52224           // [6][4][16][34] floats
#define LDSW_BYTES 98304           // 4 slots x 3 frags x 8 s x 64 lanes x 16B
#define DEC_SMEM (SACC_BYTES + LDSW_BYTES)   // 150528 <= 160 KiB

typedef __attribute__((ext_vector_type(8))) short bf16x8;
typedef __attribute__((ext_vector_type(4))) float f32x4;
typedef __attribute__((ext_vector_type(4))) unsigned short u16x4;
typedef __attribute__((ext_vector_type(8))) unsigned short u16x8;

__device__ inline unsigned short f2bf(float f) {
    union { float f; unsigned u; } v; v.f = f;
    unsigned r = v.u + 0x7fff + ((v.u >> 16) & 1);   // RNE
    return (unsigned short)(r >> 16);
}
__device__ inline float bf2f(unsigned short u) {
    union { unsigned u; float f; } v; v.u = ((unsigned)u) << 16; return v.f;
}

// Device-coherent (L2-bypassing) 16B h-fragment load: two relaxed agent-scope
// 8B atomic loads (no cache-maintenance emitted for RELAXED).
__device__ inline bf16x8 ld_h16(const unsigned short* p) {
    union { unsigned long long u[2]; bf16x8 v; } r;
    r.u[0] = __hip_atomic_load((const unsigned long long*)p,
                               __ATOMIC_RELAXED, __HIP_MEMORY_SCOPE_AGENT);
    r.u[1] = __hip_atomic_load((const unsigned long long*)(p + 4),
                               __ATOMIC_RELAXED, __HIP_MEMORY_SCOPE_AGENT);
    return r.v;
}
__device__ inline void st_h2(unsigned short* p, unsigned short v) {
    __hip_atomic_store(p, v, __ATOMIC_RELAXED, __HIP_MEMORY_SCOPE_AGENT);
}

// async global->LDS 16B/lane copy (gfx950): LDS dest = uniform base + lane*16.
__device__ inline void gload_lds16(const unsigned short* g, unsigned short* lds)
{
    __builtin_amdgcn_global_load_lds(
        (const __attribute__((address_space(1))) void*)g,
        (__attribute__((address_space(3))) void*)lds, 16, 0, 0);
}

// ---------------------------------------------------------------------------
// fp32 -> bf16 contiguous convert (n4 = element count / 4)
// ---------------------------------------------------------------------------
__global__ __launch_bounds__(256) void convbf_kernel(
    const float* __restrict__ src, unsigned short* __restrict__ dst, int n4)
{
    for (int i = blockIdx.x * 256 + threadIdx.x; i < n4; i += gridDim.x * 256) {
        float4 v = ((const float4*)src)[i];
        u16x4 o; o.x = f2bf(v.x); o.y = f2bf(v.y); o.z = f2bf(v.z); o.w = f2bf(v.w);
        ((u16x4*)dst)[i] = o;
    }
}

// ---------------------------------------------------------------------------
// Ebf[t*B+b][h] = bf16(relu(emb[token(t,b)][h]))
// ---------------------------------------------------------------------------
__global__ __launch_bounds__(256) void embed_bf_kernel(
    const int* __restrict__ target, const float* __restrict__ emb,
    unsigned short* __restrict__ Ebf)
{
    int bid = blockIdx.x;                  // t*B+b
    int t = bid >> 5, b = bid & 31;
    int tok = (t == 0) ? 0 : target[b * T_ + (t - 1)];
    float4 v = ((const float4*)(emb + (size_t)tok * H_))[threadIdx.x];
    u16x4 o;
    o.x = f2bf(fmaxf(v.x, 0.f)); o.y = f2bf(fmaxf(v.y, 0.f));
    o.z = f2bf(fmaxf(v.z, 0.f)); o.w = f2bf(fmaxf(v.w, 0.f));
    ((u16x4*)(Ebf + (size_t)bid * H_))[threadIdx.x] = o;
}

// ---------------------------------------------------------------------------
// Attention collapse (step-invariant)
// ---------------------------------------------------------------------------
__global__ __launch_bounds__(256) void attn_pre_kernel(
    const float* __restrict__ enc_h, const float* __restrict__ l1_w,
    const float* __restrict__ l1_b, const float* __restrict__ l2_w,
    float* __restrict__ Cout, float* __restrict__ scores)
{
    __shared__ float L1h[96];
    __shared__ float sc[32];
    int tid = threadIdx.x, wv = tid >> 6, lane = tid & 63;
    for (int d = wv; d < 96; d += 4) {
        int b = d / 3, g = d - 3 * b;
        const float4* wp = (const float4*)(l1_w + (size_t)g * 2 * H_ + H_);
        const float4* ep = (const float4*)(enc_h + (size_t)b * H_);
        float s = 0.f;
        for (int q = lane; q < 256; q += 64) {
            float4 w4 = wp[q], e4 = ep[q];
            s += w4.x * e4.x + w4.y * e4.y + w4.z * e4.z + w4.w * e4.w;
        }
        for (int o = 32; o > 0; o >>= 1) s += __shfl_down(s, o);
        if (lane == 0) L1h[d] = s;
    }
    __syncthreads();
    if (tid < 32) {
        float cb = 0.f;
        for (int g = 0; g < 3; ++g) cb += l2_w[g] * (L1h[tid * 3 + g] + l1_b[g]);
        sc[tid] = cb;
    }
    __syncthreads();
    if (tid == 0) {
        float m = sc[0];
        for (int b = 1; b < 32; ++b) m = fmaxf(m, sc[b]);
        float s = 0.f;
        for (int b = 0; b < 32; ++b) { float e = expf(sc[b] - m); sc[b] = e; s += e; }
        float inv = 1.f / s;
        for (int b = 0; b < 32; ++b) { sc[b] *= inv; scores[b] = sc[b]; }
    }
    __syncthreads();
    float4 c = make_float4(0.f, 0.f, 0.f, 0.f);
    for (int b = 0; b < 32; ++b) {
        float4 e = ((const float4*)(enc_h + (size_t)b * H_))[tid];
        float ww = sc[b];
        c.x += ww * e.x; c.y += ww * e.y; c.z += ww * e.z; c.w += ww * e.w;
    }
    ((float4*)Cout)[tid] = c;
}

// ---------------------------------------------------------------------------
// wcC[n] = sum_k w_ih0[n][H+k] * C[k]
// ---------------------------------------------------------------------------
__global__ __launch_bounds__(256) void wcc_kernel(
    const float* __restrict__ w_ih0, const float* __restrict__ C,
    float* __restrict__ wcC)
{
    int row = blockIdx.x * 4 + (threadIdx.x >> 6);
    int lane = threadIdx.x & 63;
    const float4* wp = (const float4*)(w_ih0 + (size_t)row * 2 * H_ + H_);
    const float4* cp = (const float4*)C;
    float s = 0.f;
    for (int q = lane; q < 256; q += 64) {
        float4 w4 = wp[q], c4 = cp[q];
        s += w4.x * c4.x + w4.y * c4.y + w4.z * c4.z + w4.w * c4.w;
    }
    for (int o = 32; o > 0; o >>= 1) s += __shfl_down(s, o);
    if (lane == 0) wcC[row] = s;
}

// ---------------------------------------------------------------------------
// LDS-staged MFMA GEMM: out[row][col] = A[row][:] . B[col][:] + bias[row]
//  outMode 0: bf16 out[col*M + row]                       (G0)
//  outMode 2: bf16 Lbf[col*V + row] + per-col (max,sumexp) partials P (logits)
// ---------------------------------------------------------------------------
__global__ __launch_bounds__(256) void gemm_staged(
    const unsigned short* __restrict__ A, int lda,
    const unsigned short* __restrict__ Bb,
    const float* __restrict__ bias, int M, int outMode,
    void* __restrict__ outp, float2* __restrict__ P)
{
    __shared__ unsigned short Wt[128 * 64];   // [row][k], 128B rows, swizzled
    __shared__ unsigned short Ht[128 * 64];
    __shared__ float2 smp[4][4][16];          // [wv][ci][rlo] partial (m,s)

    const int tid = threadIdx.x, wv = tid >> 6, lane = tid & 63;
    const int rlo = lane & 15, khw = lane >> 4;        // khw 0..3
    const int rch = lane >> 3, slot = lane & 7;        // staging roles
    const int rowB = blockIdx.y * 128, colB = blockIdx.x * 128;
    const int wrow0 = rowB + (wv >> 1) * 64;
    const int wcol0 = colB + (wv & 1) * 64;
    const int rA = (wv >> 1) * 64, cA = (wv & 1) * 64;

    f32x4 acc[4][4];
    #pragma unroll
    for (int i = 0; i < 4; ++i)
        #pragma unroll
        for (int j = 0; j < 4; ++j) acc[i][j] = (f32x4){0.f, 0.f, 0.f, 0.f};

    for (int k0 = 0; k0 < H_; k0 += 64) {
        #pragma unroll
        for (int j = 0; j < 4; ++j) {
            int q = wv * 4 + j;
            int row = q * 8 + rch;                      // 0..127
            int ss = slot ^ (row & 7);                  // pre-swizzled source
            gload_lds16(A + (size_t)(rowB + row) * lda + k0 + ss * 8,
                        Wt + (size_t)q * 512);
            gload_lds16(Bb + (size_t)(colB + row) * H_ + k0 + ss * 8,
                        Ht + (size_t)q * 512);
        }
        __syncthreads();

        const char* WtB = (const char*)Wt;
        const char* HtB = (const char*)Ht;
        #pragma unroll
        for (int kk = 0; kk < 2; ++kk) {
            bf16x8 af[4], bfr[4];
            #pragma unroll
            for (int ri = 0; ri < 4; ++ri) {
                int row = rA + ri * 16 + rlo;
                int ch = (kk * 4 + khw) ^ (row & 7);
                af[ri] = *(const bf16x8*)(WtB + row * 128 + ch * 16);
            }
            #pragma unroll
            for (int ci = 0; ci < 4; ++ci) {
                int col = cA + ci * 16 + rlo;
                int ch = (kk * 4 + khw) ^ (col & 7);
                bfr[ci] = *(const bf16x8*)(HtB + col * 128 + ch * 16);
            }
            #pragma unroll
            for (int ri = 0; ri < 4; ++ri)
                #pragma unroll
                for (int ci = 0; ci < 4; ++ci)
                    acc[ri][ci] = __builtin_amdgcn_mfma_f32_16x16x32_bf16(
                        af[ri], bfr[ci], acc[ri][ci], 0, 0, 0);
        }
        __syncthreads();
    }

    int rowoff = (lane >> 4) * 4;
    if (outMode == 0) {
        #pragma unroll
        for (int ri = 0; ri < 4; ++ri) {
            int row = wrow0 + ri * 16 + rowoff;
            float4 bs = *(const float4*)(bias + row);
            #pragma unroll
            for (int ci = 0; ci < 4; ++ci) {
                int col = wcol0 + ci * 16 + rlo;
                u16x4 o;
                o.x = f2bf(acc[ri][ci][0] + bs.x); o.y = f2bf(acc[ri][ci][1] + bs.y);
                o.z = f2bf(acc[ri][ci][2] + bs.z); o.w = f2bf(acc[ri][ci][3] + bs.w);
                *(u16x4*)((unsigned short*)outp + (size_t)col * M + row) = o;
            }
        }
        return;
    }

    // ---- outMode 2: bf16 logits + per-column online (max, sumexp) ----
    float cm[4], cs[4];
    #pragma unroll
    for (int ci = 0; ci < 4; ++ci) { cm[ci] = -INFINITY; cs[ci] = 0.f; }
    unsigned short* Lbf = (unsigned short*)outp;
    #pragma unroll
    for (int ri = 0; ri < 4; ++ri) {
        int row = wrow0 + ri * 16 + rowoff;
        float4 bs = *(const float4*)(bias + row);
        #pragma unroll
        for (int ci = 0; ci < 4; ++ci) {
            int col = wcol0 + ci * 16 + rlo;
            float4 v;
            v.x = acc[ri][ci][0] + bs.x; v.y = acc[ri][ci][1] + bs.y;
            v.z = acc[ri][ci][2] + bs.z; v.w = acc[ri][ci][3] + bs.w;
            u16x4 o; o.x = f2bf(v.x); o.y = f2bf(v.y);
            o.z = f2bf(v.z); o.w = f2bf(v.w);
            *(u16x4*)(Lbf + (size_t)col * V_ + row) = o;
            float m4 = fmaxf(fmaxf(v.x, v.y), fmaxf(v.z, v.w));
            if (m4 > cm[ci]) { cs[ci] *= __expf(cm[ci] - m4); cm[ci] = m4; }
            cs[ci] += __expf(v.x - cm[ci]) + __expf(v.y - cm[ci])
                    + __expf(v.z - cm[ci]) + __expf(v.w - cm[ci]);
        }
    }
    #pragma unroll
    for (int ci = 0; ci < 4; ++ci) {
        #pragma unroll
        for (int off = 16; off <= 32; off <<= 1) {
            float om = __shfl_xor(cm[ci], off);
            float os = __shfl_xor(cs[ci], off);
            float mm = fmaxf(cm[ci], om);
            cs[ci] = cs[ci] * __expf(cm[ci] - mm) + os * __expf(om - mm);
            cm[ci] = mm;
        }
        if ((lane >> 4) == 0) smp[wv][ci][rlo] = make_float2(cm[ci], cs[ci]);
    }
    __syncthreads();
    if (tid < 128) {
        int c = tid >> 6, ci = (tid >> 4) & 3, rl = tid & 15;
        float2 a = smp[c][ci][rl], b = smp[c + 2][ci][rl];
        float mm = fmaxf(a.x, b.x);
        float ss = a.y * __expf(a.x - mm) + b.y * __expf(b.x - mm);
        int col = colB + c * 64 + ci * 16 + rl;
        P[(size_t)blockIdx.y * TB_ + col] = make_float2(mm, ss);
    }
}

// ---------------------------------------------------------------------------
// lse[col] = merge of NVT partials
// ---------------------------------------------------------------------------
__global__ __launch_bounds__(256) void lse_finish_kernel(
    const float2* __restrict__ P, float* __restrict__ lse)
{
    int col = blockIdx.x * 256 + threadIdx.x;
    if (col >= TB_) return;
    float M = -INFINITY, S = 0.f;
    for (int i = 0; i < NVT; ++i) {
        float2 p = P[(size_t)i * TB_ + col];
        float mm = fmaxf(M, p.x);
        S = S * __expf(M - mm) + p.y * __expf(p.x - mm);
        M = mm;
    }
    lse[col] = M + logf(S);
}

// ---------------------------------------------------------------------------
// dec_out[b][t][v] = bf2f(Lbf[col][v]) - lse[col],  col = t*32+b
// ---------------------------------------------------------------------------
__global__ __launch_bounds__(256) void subtract_kernel(
    const unsigned short* __restrict__ Lbf, const float* __restrict__ lse,
    float* __restrict__ dout)
{
    int col = blockIdx.x;
    int t = col >> 5, b = col & 31;
    float l = lse[col];
    const u16x8* L = (const u16x8*)(Lbf + (size_t)col * V_);
    float4* o = (float4*)(dout + ((size_t)b * T_ + t) * V_);
    for (int i = threadIdx.x; i < V_ / 8; i += 256) {
        u16x8 x = L[i];
        float4 v0, v1;
        v0.x = bf2f(x[0]) - l; v0.y = bf2f(x[1]) - l;
        v0.z = bf2f(x[2]) - l; v0.w = bf2f(x[3]) - l;
        v1.x = bf2f(x[4]) - l; v1.y = bf2f(x[5]) - l;
        v1.z = bf2f(x[6]) - l; v1.w = bf2f(x[7]) - l;
        o[i * 2] = v0; o[i * 2 + 1] = v1;
    }
}

// ---------------------------------------------------------------------------
// Fence-free direct-poll grid barrier with s_sleep backoff (round-9 proven).
// ---------------------------------------------------------------------------
__device__ inline void grid_bar4(unsigned* flags, unsigned round)
{
    __syncthreads();
    if (threadIdx.x == 0) {
        asm volatile("s_waitcnt vmcnt(0)" ::: "memory");
        __hip_atomic_store(&flags[(size_t)blockIdx.x * FSTRIDE], round,
                           __ATOMIC_RELAXED, __HIP_MEMORY_SCOPE_AGENT);
    }
    int ok = (threadIdx.x >= NBLK) ? 1 : 0;
    while (true) {
        if (!ok)
            ok = (__hip_atomic_load(&flags[(size_t)threadIdx.x * FSTRIDE],
                                    __ATOMIC_RELAXED, __HIP_MEMORY_SCOPE_AGENT) >= round);
        if (__syncthreads_and(ok)) break;
        __builtin_amdgcn_s_sleep(2);
    }
}

// ---------------------------------------------------------------------------
// Persistent pipelined decode (round-11 structure) + LDS weight cache.
// Per block: half the weight set (kc in {0,1}, 96 KB bf16) is copied to LDS
// once and read from LDS every round; the streamed half (kc in {2,3}) drops
// the per-XCD weight working set to 28 x 98 KB = 2.75 MB < 4 MiB L2 ->
// L2-resident. Dynamic LDS = 52224 (sacc) + 98304 (weights) = 150528 B.
// ---------------------------------------------------------------------------
__global__ __launch_bounds__(512, 1) void decode_kernel(
    const unsigned short* __restrict__ whh0_bf,   // [3H][H]
    const unsigned short* __restrict__ wih_bf,    // [3][3H][H]
    const unsigned short* __restrict__ whh_bf,    // [3][3H][H]
    const unsigned short* __restrict__ G0,        // [TB][3H] bf16
    const float* __restrict__ b_ih0, const float* __restrict__ b_hh0,
    const float* __restrict__ b_ih,  const float* __restrict__ b_hh,
    const float* __restrict__ enc_hidden,         // [L][B][H] fp32
    unsigned short* __restrict__ hbf,             // [2][L][B][H] bf16
    unsigned short* __restrict__ Hist,            // [TB][H] bf16
    float* __restrict__ hid_out,                  // d_out + B*T*V
    unsigned* __restrict__ flags)
{
    extern __shared__ char smem[];
    float (*sacc)[4][16][34] = (float (*)[4][16][34])smem;   // [6][4][16][34]
    unsigned short* ldsw = (unsigned short*)(smem + SACC_BYTES);

    const int tid = threadIdx.x;
    const int wv = tid >> 6, lane = tid & 63;
    const int rlo = lane & 15, klane = (lane >> 4) * 8;
    const int rowoff = (lane >> 4) * 4;
    const int bid = blockIdx.x;

    int layer, f0;
    if (bid < L0BLK) { layer = 0; f0 = bid << 5; }
    else { int r = bid - L0BLK; layer = 1 + (r >> 6); f0 = (r & 63) << 4; }

    const unsigned short* Wih_l = (layer >= 1) ? wih_bf + (size_t)(layer - 1) * N3H * H_ : nullptr;
    const unsigned short* Whh_l = (layer >= 1) ? whh_bf + (size_t)(layer - 1) * N3H * H_ : whh0_bf;

    const int kc = wv & 3, srcgrp = wv >> 2;
    const bool useLds = (kc < 2);
    const int lslot = srcgrp * 2 + kc;            // 0..3 when useLds
    unsigned short* lw = ldsw + (size_t)lslot * 12288;   // 24576 B per slot

    // ---- weight preload; LDS-cache the kc<2 half ----
    const unsigned short* wp[3];
    int rgv[3];
    #pragma unroll
    for (int i = 0; i < 3; ++i) {
        int rg = srcgrp * 3 + i;
        rgv[i] = rg;
        int wrow; const unsigned short* Wm;
        if (layer == 0)      { wrow = (rg >> 1) * H_ + f0 + (rg & 1) * 16; Wm = Whh_l; }
        else if (rg < 3)     { wrow = rg * H_ + f0;        Wm = Wih_l; }
        else                 { wrow = (rg - 3) * H_ + f0;  Wm = Whh_l; }
        wp[i] = Wm + (size_t)(wrow + rlo) * H_ + kc * 256 + klane;
    }
    if (useLds) {
        #pragma unroll
        for (int i = 0; i < 3; ++i)
            #pragma unroll
            for (int s = 0; s < 8; ++s)
                *(bf16x8*)(lw + ((i * 8 + s) * 64 + lane) * 8) =
                    *(const bf16x8*)(wp[i] + s * 32);
    }
    __syncthreads();

    // ---- bias + hold-state registers ----
    const float* bihp = (layer == 0) ? b_ih0 : b_ih + (size_t)(layer - 1) * N3H;
    const float* bhhp = (layer == 0) ? b_hh0 : b_hh + (size_t)(layer - 1) * N3H;
    int jj, eb0;
    float hold0, hold1 = 0.f;
    if (layer == 0) {
        jj = f0 + (tid & 31);
        eb0 = tid >> 5;
        hold0 = enc_hidden[(size_t)eb0 * H_ + jj];
        hold1 = enc_hidden[(size_t)(eb0 + 16) * H_ + jj];
    } else {
        jj = f0 + (tid & 15);               // coalesced epilogue stores
        eb0 = tid >> 4;
        hold0 = enc_hidden[(size_t)layer * B_ * H_ + (size_t)eb0 * H_ + jj];
    }
    const float bir = bihp[jj], biz = bihp[H_ + jj], bin_ = bihp[2 * H_ + jj];
    const float bhr = bhhp[jj], bhz = bhhp[H_ + jj], bhn = bhhp[2 * H_ + jj];

    const size_t BH = (size_t)B_ * H_;

    for (int c = 0; c < T_ + L_ - 1; ++c) {
        int t = c - layer;
        if (t >= 0 && t < T_) {
            int pw = t & 1, pr = pw ^ 1;
            const unsigned short* hown  = hbf + ((size_t)pr * L_ + layer) * BH;
            const unsigned short* hprev = (layer > 0)
                ? hbf + ((size_t)pw * L_ + (layer - 1)) * BH : nullptr;

            f32x4 acc[3][2];
            #pragma unroll
            for (int i = 0; i < 3; ++i) {
                acc[i][0] = (f32x4){0.f, 0.f, 0.f, 0.f};
                acc[i][1] = (f32x4){0.f, 0.f, 0.f, 0.f};
            }

            const unsigned short* hsrc = (layer == 0 || srcgrp == 1) ? hown : hprev;
            const unsigned short* hp = hsrc + (size_t)rlo * H_ + kc * 256 + klane;
            if (useLds) {
                #pragma unroll
                for (int s = 0; s < 8; ++s) {
                    bf16x8 b0 = ld_h16(hp + s * 32);
                    bf16x8 b1 = ld_h16(hp + 16 * H_ + s * 32);
                    #pragma unroll
                    for (int i = 0; i < 3; ++i) {
                        bf16x8 a = *(const bf16x8*)(lw + ((i * 8 + s) * 64 + lane) * 8);
                        acc[i][0] = __builtin_amdgcn_mfma_f32_16x16x32_bf16(a, b0, acc[i][0], 0, 0, 0);
                        acc[i][1] = __builtin_amdgcn_mfma_f32_16x16x32_bf16(a, b1, acc[i][1], 0, 0, 0);
                    }
                }
            } else {
                #pragma unroll
                for (int s = 0; s < 8; ++s) {
                    bf16x8 b0 = ld_h16(hp + s * 32);
                    bf16x8 b1 = ld_h16(hp + 16 * H_ + s * 32);
                    #pragma unroll
                    for (int i = 0; i < 3; ++i) {
                        bf16x8 a = *(const bf16x8*)(wp[i] + s * 32);
                        acc[i][0] = __builtin_amdgcn_mfma_f32_16x16x32_bf16(a, b0, acc[i][0], 0, 0, 0);
                        acc[i][1] = __builtin_amdgcn_mfma_f32_16x16x32_bf16(a, b1, acc[i][1], 0, 0, 0);
                    }
                }
            }

            #pragma unroll
            for (int i = 0; i < 3; ++i)
                #pragma unroll
                for (int r = 0; r < 4; ++r) {
                    sacc[rgv[i]][kc][rowoff + r][rlo]      = acc[i][0][r];
                    sacc[rgv[i]][kc][rowoff + r][16 + rlo] = acc[i][1][r];
                }
            __syncthreads();

            if (layer > 0) {
                int f = tid & 15, b = tid >> 4;
                float ir = bir, iz = biz, in_ = bin_;
                float hr = bhr, hz = bhz, hn = bhn;
                #pragma unroll
                for (int k2 = 0; k2 < 4; ++k2) {
                    ir += sacc[0][k2][f][b]; iz += sacc[1][k2][f][b]; in_ += sacc[2][k2][f][b];
                    hr += sacc[3][k2][f][b]; hz += sacc[4][k2][f][b]; hn += sacc[5][k2][f][b];
                }
                float r = 1.f / (1.f + expf(-(ir + hr)));
                float z = 1.f / (1.f + expf(-(iz + hz)));
                float n = tanhf(in_ + r * hn);
                float hnew = (1.f - z) * n + z * hold0;
                hold0 = hnew;
                unsigned short hb16 = f2bf(hnew);
                st_h2(&hbf[((size_t)pw * L_ + layer) * BH + (size_t)b * H_ + jj], hb16);
                if (layer == L_ - 1) Hist[((size_t)t * B_ + b) * H_ + jj] = hb16;
                if (t == T_ - 1) hid_out[(size_t)layer * BH + (size_t)b * H_ + jj] = hnew;
            } else {
                int fi = tid & 31;
                int rghalf = fi >> 4, fr = fi & 15;
                {
                    int b = eb0;
                    const unsigned short* g0p = G0 + ((size_t)t * B_ + b) * N3H;
                    float ir = bf2f(g0p[jj]) + bir;
                    float iz = bf2f(g0p[H_ + jj]) + biz;
                    float in_ = bf2f(g0p[2 * H_ + jj]) + bin_;
                    float hr = bhr, hz = bhz, hn = bhn;
                    #pragma unroll
                    for (int k2 = 0; k2 < 4; ++k2) {
                        hr += sacc[rghalf][k2][fr][b];
                        hz += sacc[2 + rghalf][k2][fr][b];
                        hn += sacc[4 + rghalf][k2][fr][b];
                    }
                    float r = 1.f / (1.f + expf(-(ir + hr)));
                    float z = 1.f / (1.f + expf(-(iz + hz)));
                    float n = tanhf(in_ + r * hn);
                    float hnew = (1.f - z) * n + z * hold0;
                    hold0 = hnew;
                    st_h2(&hbf[((size_t)pw * L_) * BH + (size_t)b * H_ + jj], f2bf(hnew));
                    if (t == T_ - 1) hid_out[(size_t)b * H_ + jj] = hnew;
                }
                {
                    int b = eb0 + 16;
                    const unsigned short* g0p = G0 + ((size_t)t * B_ + b) * N3H;
                    float ir = bf2f(g0p[jj]) + bir;
                    float iz = bf2f(g0p[H_ + jj]) + biz;
                    float in_ = bf2f(g0p[2 * H_ + jj]) + bin_;
                    float hr = bhr, hz = bhz, hn = bhn;
                    #pragma unroll
                    for (int k2 = 0; k2 < 4; ++k2) {
                        hr += sacc[rghalf][k2][fr][b];
                        hz += sacc[2 + rghalf][k2][fr][b];
                        hn += sacc[4 + rghalf][k2][fr][b];
                    }
                    float r = 1.f / (1.f + expf(-(ir + hr)));
                    float z = 1.f / (1.f + expf(-(iz + hz)));
                    float n = tanhf(in_ + r * hn);
                    float hnew = (1.f - z) * n + z * hold1;
                    hold1 = hnew;
                    st_h2(&hbf[((size_t)pw * L_) * BH + (size_t)b * H_ + jj], f2bf(hnew));
                    if (t == T_ - 1) hid_out[(size_t)b * H_ + jj] = hnew;
                }
            }
        }
        grid_bar4(flags, (unsigned)(c + 1));
    }
}

// ---------------------------------------------------------------------------
// Fallback in-place log_softmax + fp32 logits GEMM (workspace-short path)
// ---------------------------------------------------------------------------
__global__ __launch_bounds__(256) void logsoftmax_kernel(float* __restrict__ dout)
{
    __shared__ float red[256];
    float4* x4 = (float4*)(dout + (size_t)blockIdx.x * V_);
    const int N4 = V_ / 4;
    int tid = threadIdx.x;

    float m = -INFINITY, s = 0.f;
    for (int i = tid; i < N4; i += 256) {
        float4 v = x4[i];
        float m4 = fmaxf(fmaxf(v.x, v.y), fmaxf(v.z, v.w));
        if (m4 > m) { s *= expf(m - m4); m = m4; }
        s += expf(v.x - m) + expf(v.y - m) + expf(v.z - m) + expf(v.w - m);
    }
    red[tid] = m; __syncthreads();
    for (int o = 128; o > 0; o >>= 1) {
        if (tid < o) red[tid] = fmaxf(red[tid], red[tid + o]);
        __syncthreads();
    }
    float M = red[0]; __syncthreads();
    red[tid] = s * expf(m - M); __syncthreads();
    for (int o = 128; o > 0; o >>= 1) {
        if (tid < o) red[tid] += red[tid + o];
        __syncthreads();
    }
    float lse = M + logf(red[0]);

    for (int i = tid; i < N4; i += 256) {
        float4 v = x4[i];
        v.x -= lse; v.y -= lse; v.z -= lse; v.w -= lse;
        x4[i] = v;
    }
}

__global__ __launch_bounds__(256) void gemm_logits_f32(
    const unsigned short* __restrict__ A,
    const unsigned short* __restrict__ Bb,
    const float* __restrict__ bias, float* __restrict__ dout)
{
    __shared__ unsigned short Wt[128 * 64];
    __shared__ unsigned short Ht[128 * 64];
    const int tid = threadIdx.x, wv = tid >> 6, lane = tid & 63;
    const int rlo = lane & 15, khw = lane >> 4;
    const int rch = lane >> 3, slot = lane & 7;
    const int rowB = blockIdx.y * 128, colB = blockIdx.x * 128;
    const int wrow0 = rowB + (wv >> 1) * 64;
    const int wcol0 = colB + (wv & 1) * 64;
    const int rA = (wv >> 1) * 64, cA = (wv & 1) * 64;

    f32x4 acc[4][4];
    #pragma unroll
    for (int i = 0; i < 4; ++i)
        #pragma unroll
        for (int j = 0; j < 4; ++j) acc[i][j] = (f32x4){0.f, 0.f, 0.f, 0.f};

    for (int k0 = 0; k0 < H_; k0 += 64) {
        #pragma unroll
        for (int j = 0; j < 4; ++j) {
            int q = wv * 4 + j;
            int row = q * 8 + rch;
            int ss = slot ^ (row & 7);
            gload_lds16(A + (size_t)(rowB + row) * H_ + k0 + ss * 8, Wt + (size_t)q * 512);
            gload_lds16(Bb + (size_t)(colB + row) * H_ + k0 + ss * 8, Ht + (size_t)q * 512);
        }
        __syncthreads();
        const char* WtB = (const char*)Wt;
        const char* HtB = (const char*)Ht;
        #pragma unroll
        for (int kk = 0; kk < 2; ++kk) {
            bf16x8 af[4], bfr[4];
            #pragma unroll
            for (int ri = 0; ri < 4; ++ri) {
                int row = rA + ri * 16 + rlo;
                int ch = (kk * 4 + khw) ^ (row & 7);
                af[ri] = *(const bf16x8*)(WtB + row * 128 + ch * 16);
            }
            #pragma unroll
            for (int ci = 0; ci < 4; ++ci) {
                int col = cA + ci * 16 + rlo;
                int ch = (kk * 4 + khw) ^ (col & 7);
                bfr[ci] = *(const bf16x8*)(HtB + col * 128 + ch * 16);
            }
            #pragma unroll
            for (int ri = 0; ri < 4; ++ri)
                #pragma unroll
                for (int ci = 0; ci < 4; ++ci)
                    acc[ri][ci] = __builtin_amdgcn_mfma_f32_16x16x32_bf16(
                        af[ri], bfr[ci], acc[ri][ci], 0, 0, 0);
        }
        __syncthreads();
    }
    int rowoff = (lane >> 4) * 4;
    #pragma unroll
    for (int ri = 0; ri < 4; ++ri) {
        int row = wrow0 + ri * 16 + rowoff;
        float4 bs = *(const float4*)(bias + row);
        #pragma unroll
        for (int ci = 0; ci < 4; ++ci) {
            int col = wcol0 + ci * 16 + rlo;
            int tt = col >> 5, b = col & 31;
            float4 v;
            v.x = acc[ri][ci][0] + bs.x; v.y = acc[ri][ci][1] + bs.y;
            v.z = acc[ri][ci][2] + bs.z; v.w = acc[ri][ci][3] + bs.w;
            *(float4*)(dout + ((size_t)b * T_ + tt) * V_ + row) = v;
        }
    }
}

// ---------------------------------------------------------------------------
extern "C" void kernel_launch(void* const* d_in, const int* in_sizes, int n_in,
                              void* d_out, int out_size, void* d_ws, size_t ws_size,
                              hipStream_t stream)
{
    (void)in_sizes; (void)n_in; (void)out_size;

    const float* enc_hidden = (const float*)d_in[1];   // [L][B][H]; layer0 = enc_h
    const int*   target     = (const int*)  d_in[2];
    const float* emb        = (const float*)d_in[3];
    const float* w_ih0      = (const float*)d_in[4];   // [3H][2H]
    const float* w_hh0      = (const float*)d_in[5];   // [3H][H]
    const float* b_ih0      = (const float*)d_in[6];
    const float* b_hh0      = (const float*)d_in[7];
    const float* w_ih       = (const float*)d_in[8];   // [3][3H][H]
    const float* w_hh       = (const float*)d_in[9];
    const float* b_ih       = (const float*)d_in[10];
    const float* b_hh       = (const float*)d_in[11];
    const float* out_w      = (const float*)d_in[12];  // [V][H]
    const float* out_b      = (const float*)d_in[13];
    const float* l1_w       = (const float*)d_in[14];
    const float* l1_b       = (const float*)d_in[15];
    const float* l2_w       = (const float*)d_in[16];
    float* out = (float*)d_out;

    // --- workspace carve ---
    char* w = (char*)d_ws;
    auto alloc = [&](size_t bytes) -> char* {
        char* p = w; w += (bytes + 255) & ~(size_t)255; return p;
    };
    unsigned short* whh0_bf = (unsigned short*)alloc((size_t)N3H * H_ * 2);
    unsigned short* wih_bf  = (unsigned short*)alloc((size_t)3 * N3H * H_ * 2);
    unsigned short* whh_bf  = (unsigned short*)alloc((size_t)3 * N3H * H_ * 2);
    unsigned short* Ebf     = (unsigned short*)alloc((size_t)TB_ * H_ * 2);
    unsigned short* G0      = (unsigned short*)alloc((size_t)TB_ * N3H * 2);
    unsigned short* Hist    = (unsigned short*)alloc((size_t)TB_ * H_ * 2);
    unsigned short* hbf     = (unsigned short*)alloc((size_t)2 * L_ * B_ * H_ * 2);
    float*          Cbuf    = (float*)alloc(H_ * 4);
    float*          scores  = (float*)alloc(256);
    float*          wcC     = (float*)alloc(N3H * 4);
    unsigned*       flags   = (unsigned*)alloc((size_t)NBLK * FSTRIDE * 4);
    float2*         Ppart   = (float2*)alloc((size_t)NVT * TB_ * 8);      // 6.4 MB
    float*          lse     = (float*)alloc((size_t)TB_ * 4);

    size_t used = (size_t)(w - (char*)d_ws);
    unsigned short* wih0f_bf = nullptr;     // full w_ih0 in bf16 [3H][2H]
    if (used + (size_t)N3H * 2 * H_ * 2 + 256 <= ws_size)
        wih0f_bf = (unsigned short*)alloc((size_t)N3H * 2 * H_ * 2);
    used = (size_t)(w - (char*)d_ws);
    unsigned short* outw_bf = nullptr;
    if (used + (size_t)V_ * H_ * 2 + 256 <= ws_size)
        outw_bf = (unsigned short*)alloc((size_t)V_ * H_ * 2);
    used = (size_t)(w - (char*)d_ws);
    unsigned short* Lbf = nullptr;          // bf16 logits [TB][V] = 204.8 MB
    if (used + (size_t)TB_ * V_ * 2 + 256 <= ws_size)
        Lbf = (unsigned short*)alloc((size_t)TB_ * V_ * 2);

    const size_t LBH = (size_t)L_ * B_ * H_;

    hipMemsetAsync(flags, 0, (size_t)NBLK * FSTRIDE * 4, stream);

    // --- one-time precompute ---
    convbf_kernel<<<512, 256, 0, stream>>>(w_hh0, whh0_bf, N3H * H_ / 4);
    convbf_kernel<<<1024, 256, 0, stream>>>(w_ih, wih_bf, 3 * N3H * H_ / 4);
    convbf_kernel<<<1024, 256, 0, stream>>>(w_hh, whh_bf, 3 * N3H * H_ / 4);
    if (wih0f_bf)
        convbf_kernel<<<1024, 256, 0, stream>>>(w_ih0, wih0f_bf, N3H * 2 * H_ / 4);
    if (outw_bf)
        convbf_kernel<<<2048, 256, 0, stream>>>(out_w, outw_bf, V_ * H_ / 4);
    embed_bf_kernel<<<TB_, 256, 0, stream>>>(target, emb, Ebf);
    convbf_kernel<<<128, 256, 0, stream>>>(enc_hidden, hbf + LBH, (int)(LBH / 4));
    attn_pre_kernel<<<1, 256, 0, stream>>>(enc_hidden, l1_w, l1_b, l2_w, Cbuf, scores);
    wcc_kernel<<<N3H / 4, 256, 0, stream>>>(w_ih0, Cbuf, wcC);

    // G0 = W_E @ E (+ wcC bias)
    gemm_staged<<<dim3(TB_ / 128, N3H / 128), 256, 0, stream>>>(
        wih0f_bf, 2 * H_, Ebf, wcC, N3H, 0, G0, nullptr);

    // --- persistent pipelined decode (dynamic LDS: sacc + weight cache) ---
    hipFuncSetAttribute((const void*)decode_kernel,
                        hipFuncAttributeMaxDynamicSharedMemorySize, DEC_SMEM);
    decode_kernel<<<NBLK, 512, DEC_SMEM, stream>>>(
        whh0_bf, wih_bf, whh_bf, G0, b_ih0, b_hh0, b_ih, b_hh,
        enc_hidden, hbf, Hist, out + (size_t)B_ * T_ * V_, flags);

    // --- deferred logits GEMM + fused log_softmax ---
    if (outw_bf && Lbf) {
        gemm_staged<<<dim3(TB_ / 128, V_ / 128), 256, 0, stream>>>(
            outw_bf, H_, Hist, out_b, V_, 2, Lbf, Ppart);
        lse_finish_kernel<<<(TB_ + 255) / 256, 256, 0, stream>>>(Ppart, lse);
        subtract_kernel<<<TB_, 256, 0, stream>>>(Lbf, lse, out);
    } else if (outw_bf) {
        gemm_logits_f32<<<dim3(TB_ / 128, V_ / 128), 256, 0, stream>>>(
            outw_bf, Hist, out_b, out);
        logsoftmax_kernel<<<TB_, 256, 0, stream>>>(out);
    }

    hipMemcpyAsync(out + (size_t)B_ * T_ * V_ + LBH, scores, B_ * 4,
                   hipMemcpyDeviceToDevice, stream);
}

// Round 15
// 1792.698 us; speedup vs baseline: 1.3549x; 1.2170x over previous
//
#include <hip/hip_runtime.h>
#include <hip/hip_bf16.h>
#include <math.h>

#define B_ 32
#define H_ 1024
#define V_ 32000
#define T_ 100
#define L_ 4
#define TB_ (T_*B_)      // 3200
#define N3H (3*H_)       // 3072
#define NBLK 224         // decode grid: 32 (layer0) + 3*64 (layers 1-3)
#define L0BLK 32
#define FSTRIDE 16       // flag padding: 16 uints = 64B per block
#define NVT (V_/128)     // 250 logits row tiles

typedef __attribute__((ext_vector_type(8))) short bf16x8;
typedef __attribute__((ext_vector_type(4))) float f32x4;
typedef __attribute__((ext_vector_type(4))) unsigned short u16x4;
typedef __attribute__((ext_vector_type(8))) unsigned short u16x8;

__device__ inline unsigned short f2bf(float f) {
    union { float f; unsigned u; } v; v.f = f;
    unsigned r = v.u + 0x7fff + ((v.u >> 16) & 1);   // RNE
    return (unsigned short)(r >> 16);
}
__device__ inline float bf2f(unsigned short u) {
    union { unsigned u; float f; } v; v.u = ((unsigned)u) << 16; return v.f;
}

// Device-coherent (L2-bypassing) 16B h-fragment load: two relaxed agent-scope
// 8B atomic loads (no cache-maintenance emitted for RELAXED).
__device__ inline bf16x8 ld_h16(const unsigned short* p) {
    union { unsigned long long u[2]; bf16x8 v; } r;
    r.u[0] = __hip_atomic_load((const unsigned long long*)p,
                               __ATOMIC_RELAXED, __HIP_MEMORY_SCOPE_AGENT);
    r.u[1] = __hip_atomic_load((const unsigned long long*)(p + 4),
                               __ATOMIC_RELAXED, __HIP_MEMORY_SCOPE_AGENT);
    return r.v;
}
__device__ inline void st_h2(unsigned short* p, unsigned short v) {
    __hip_atomic_store(p, v, __ATOMIC_RELAXED, __HIP_MEMORY_SCOPE_AGENT);
}

// async global->LDS 16B/lane copy (gfx950): LDS dest = uniform base + lane*16.
__device__ inline void gload_lds16(const unsigned short* g, unsigned short* lds)
{
    __builtin_amdgcn_global_load_lds(
        (const __attribute__((address_space(1))) void*)g,
        (__attribute__((address_space(3))) void*)lds, 16, 0, 0);
}

// ---------------------------------------------------------------------------
// fp32 -> bf16 contiguous convert (n4 = element count / 4)
// ---------------------------------------------------------------------------
__global__ __launch_bounds__(256) void convbf_kernel(
    const float* __restrict__ src, unsigned short* __restrict__ dst, int n4)
{
    for (int i = blockIdx.x * 256 + threadIdx.x; i < n4; i += gridDim.x * 256) {
        float4 v = ((const float4*)src)[i];
        u16x4 o; o.x = f2bf(v.x); o.y = f2bf(v.y); o.z = f2bf(v.z); o.w = f2bf(v.w);
        ((u16x4*)dst)[i] = o;
    }
}

// ---------------------------------------------------------------------------
// Ebf[t*B+b][h] = bf16(relu(emb[token(t,b)][h]))
// ---------------------------------------------------------------------------
__global__ __launch_bounds__(256) void embed_bf_kernel(
    const int* __restrict__ target, const float* __restrict__ emb,
    unsigned short* __restrict__ Ebf)
{
    int bid = blockIdx.x;                  // t*B+b
    int t = bid >> 5, b = bid & 31;
    int tok = (t == 0) ? 0 : target[b * T_ + (t - 1)];
    float4 v = ((const float4*)(emb + (size_t)tok * H_))[threadIdx.x];
    u16x4 o;
    o.x = f2bf(fmaxf(v.x, 0.f)); o.y = f2bf(fmaxf(v.y, 0.f));
    o.z = f2bf(fmaxf(v.z, 0.f)); o.w = f2bf(fmaxf(v.w, 0.f));
    ((u16x4*)(Ebf + (size_t)bid * H_))[threadIdx.x] = o;
}

// ---------------------------------------------------------------------------
// Attention collapse (step-invariant)
// ---------------------------------------------------------------------------
__global__ __launch_bounds__(256) void attn_pre_kernel(
    const float* __restrict__ enc_h, const float* __restrict__ l1_w,
    const float* __restrict__ l1_b, const float* __restrict__ l2_w,
    float* __restrict__ Cout, float* __restrict__ scores)
{
    __shared__ float L1h[96];
    __shared__ float sc[32];
    int tid = threadIdx.x, wv = tid >> 6, lane = tid & 63;
    for (int d = wv; d < 96; d += 4) {
        int b = d / 3, g = d - 3 * b;
        const float4* wp = (const float4*)(l1_w + (size_t)g * 2 * H_ + H_);
        const float4* ep = (const float4*)(enc_h + (size_t)b * H_);
        float s = 0.f;
        for (int q = lane; q < 256; q += 64) {
            float4 w4 = wp[q], e4 = ep[q];
            s += w4.x * e4.x + w4.y * e4.y + w4.z * e4.z + w4.w * e4.w;
        }
        for (int o = 32; o > 0; o >>= 1) s += __shfl_down(s, o);
        if (lane == 0) L1h[d] = s;
    }
    __syncthreads();
    if (tid < 32) {
        float cb = 0.f;
        for (int g = 0; g < 3; ++g) cb += l2_w[g] * (L1h[tid * 3 + g] + l1_b[g]);
        sc[tid] = cb;
    }
    __syncthreads();
    if (tid == 0) {
        float m = sc[0];
        for (int b = 1; b < 32; ++b) m = fmaxf(m, sc[b]);
        float s = 0.f;
        for (int b = 0; b < 32; ++b) { float e = expf(sc[b] - m); sc[b] = e; s += e; }
        float inv = 1.f / s;
        for (int b = 0; b < 32; ++b) { sc[b] *= inv; scores[b] = sc[b]; }
    }
    __syncthreads();
    float4 c = make_float4(0.f, 0.f, 0.f, 0.f);
    for (int b = 0; b < 32; ++b) {
        float4 e = ((const float4*)(enc_h + (size_t)b * H_))[tid];
        float ww = sc[b];
        c.x += ww * e.x; c.y += ww * e.y; c.z += ww * e.z; c.w += ww * e.w;
    }
    ((float4*)Cout)[tid] = c;
}

// ---------------------------------------------------------------------------
// wcC[n] = sum_k w_ih0[n][H+k] * C[k]
// ---------------------------------------------------------------------------
__global__ __launch_bounds__(256) void wcc_kernel(
    const float* __restrict__ w_ih0, const float* __restrict__ C,
    float* __restrict__ wcC)
{
    int row = blockIdx.x * 4 + (threadIdx.x >> 6);
    int lane = threadIdx.x & 63;
    const float4* wp = (const float4*)(w_ih0 + (size_t)row * 2 * H_ + H_);
    const float4* cp = (const float4*)C;
    float s = 0.f;
    for (int q = lane; q < 256; q += 64) {
        float4 w4 = wp[q], c4 = cp[q];
        s += w4.x * c4.x + w4.y * c4.y + w4.z * c4.z + w4.w * c4.w;
    }
    for (int o = 32; o > 0; o >>= 1) s += __shfl_down(s, o);
    if (lane == 0) wcC[row] = s;
}

// ---------------------------------------------------------------------------
// LDS-staged MFMA GEMM: out[row][col] = A[row][:] . B[col][:] + bias[row]
//  outMode 0: bf16 out[col*M + row]                       (G0)
//  outMode 2: bf16 Lbf[col*V + row] + per-col (max,sumexp) partials P (logits)
// ---------------------------------------------------------------------------
__global__ __launch_bounds__(256) void gemm_staged(
    const unsigned short* __restrict__ A, int lda,
    const unsigned short* __restrict__ Bb,
    const float* __restrict__ bias, int M, int outMode,
    void* __restrict__ outp, float2* __restrict__ P)
{
    __shared__ unsigned short Wt[128 * 64];   // [row][k], 128B rows, swizzled
    __shared__ unsigned short Ht[128 * 64];
    __shared__ float2 smp[4][4][16];          // [wv][ci][rlo] partial (m,s)

    const int tid = threadIdx.x, wv = tid >> 6, lane = tid & 63;
    const int rlo = lane & 15, khw = lane >> 4;        // khw 0..3
    const int rch = lane >> 3, slot = lane & 7;        // staging roles
    const int rowB = blockIdx.y * 128, colB = blockIdx.x * 128;
    const int wrow0 = rowB + (wv >> 1) * 64;
    const int wcol0 = colB + (wv & 1) * 64;
    const int rA = (wv >> 1) * 64, cA = (wv & 1) * 64;

    f32x4 acc[4][4];
    #pragma unroll
    for (int i = 0; i < 4; ++i)
        #pragma unroll
        for (int j = 0; j < 4; ++j) acc[i][j] = (f32x4){0.f, 0.f, 0.f, 0.f};

    for (int k0 = 0; k0 < H_; k0 += 64) {
        #pragma unroll
        for (int j = 0; j < 4; ++j) {
            int q = wv * 4 + j;
            int row = q * 8 + rch;                      // 0..127
            int ss = slot ^ (row & 7);                  // pre-swizzled source
            gload_lds16(A + (size_t)(rowB + row) * lda + k0 + ss * 8,
                        Wt + (size_t)q * 512);
            gload_lds16(Bb + (size_t)(colB + row) * H_ + k0 + ss * 8,
                        Ht + (size_t)q * 512);
        }
        __syncthreads();

        const char* WtB = (const char*)Wt;
        const char* HtB = (const char*)Ht;
        #pragma unroll
        for (int kk = 0; kk < 2; ++kk) {
            bf16x8 af[4], bfr[4];
            #pragma unroll
            for (int ri = 0; ri < 4; ++ri) {
                int row = rA + ri * 16 + rlo;
                int ch = (kk * 4 + khw) ^ (row & 7);
                af[ri] = *(const bf16x8*)(WtB + row * 128 + ch * 16);
            }
            #pragma unroll
            for (int ci = 0; ci < 4; ++ci) {
                int col = cA + ci * 16 + rlo;
                int ch = (kk * 4 + khw) ^ (col & 7);
                bfr[ci] = *(const bf16x8*)(HtB + col * 128 + ch * 16);
            }
            #pragma unroll
            for (int ri = 0; ri < 4; ++ri)
                #pragma unroll
                for (int ci = 0; ci < 4; ++ci)
                    acc[ri][ci] = __builtin_amdgcn_mfma_f32_16x16x32_bf16(
                        af[ri], bfr[ci], acc[ri][ci], 0, 0, 0);
        }
        __syncthreads();
    }

    int rowoff = (lane >> 4) * 4;
    if (outMode == 0) {
        #pragma unroll
        for (int ri = 0; ri < 4; ++ri) {
            int row = wrow0 + ri * 16 + rowoff;
            float4 bs = *(const float4*)(bias + row);
            #pragma unroll
            for (int ci = 0; ci < 4; ++ci) {
                int col = wcol0 + ci * 16 + rlo;
                u16x4 o;
                o.x = f2bf(acc[ri][ci][0] + bs.x); o.y = f2bf(acc[ri][ci][1] + bs.y);
                o.z = f2bf(acc[ri][ci][2] + bs.z); o.w = f2bf(acc[ri][ci][3] + bs.w);
                *(u16x4*)((unsigned short*)outp + (size_t)col * M + row) = o;
            }
        }
        return;
    }

    // ---- outMode 2: bf16 logits + per-column online (max, sumexp) ----
    float cm[4], cs[4];
    #pragma unroll
    for (int ci = 0; ci < 4; ++ci) { cm[ci] = -INFINITY; cs[ci] = 0.f; }
    unsigned short* Lbf = (unsigned short*)outp;
    #pragma unroll
    for (int ri = 0; ri < 4; ++ri) {
        int row = wrow0 + ri * 16 + rowoff;
        float4 bs = *(const float4*)(bias + row);
        #pragma unroll
        for (int ci = 0; ci < 4; ++ci) {
            int col = wcol0 + ci * 16 + rlo;
            float4 v;
            v.x = acc[ri][ci][0] + bs.x; v.y = acc[ri][ci][1] + bs.y;
            v.z = acc[ri][ci][2] + bs.z; v.w = acc[ri][ci][3] + bs.w;
            u16x4 o; o.x = f2bf(v.x); o.y = f2bf(v.y);
            o.z = f2bf(v.z); o.w = f2bf(v.w);
            *(u16x4*)(Lbf + (size_t)col * V_ + row) = o;
            float m4 = fmaxf(fmaxf(v.x, v.y), fmaxf(v.z, v.w));
            if (m4 > cm[ci]) { cs[ci] *= __expf(cm[ci] - m4); cm[ci] = m4; }
            cs[ci] += __expf(v.x - cm[ci]) + __expf(v.y - cm[ci])
                    + __expf(v.z - cm[ci]) + __expf(v.w - cm[ci]);
        }
    }
    #pragma unroll
    for (int ci = 0; ci < 4; ++ci) {
        #pragma unroll
        for (int off = 16; off <= 32; off <<= 1) {
            float om = __shfl_xor(cm[ci], off);
            float os = __shfl_xor(cs[ci], off);
            float mm = fmaxf(cm[ci], om);
            cs[ci] = cs[ci] * __expf(cm[ci] - mm) + os * __expf(om - mm);
            cm[ci] = mm;
        }
        if ((lane >> 4) == 0) smp[wv][ci][rlo] = make_float2(cm[ci], cs[ci]);
    }
    __syncthreads();
    if (tid < 128) {
        int c = tid >> 6, ci = (tid >> 4) & 3, rl = tid & 15;
        float2 a = smp[c][ci][rl], b = smp[c + 2][ci][rl];
        float mm = fmaxf(a.x, b.x);
        float ss = a.y * __expf(a.x - mm) + b.y * __expf(b.x - mm);
        int col = colB + c * 64 + ci * 16 + rl;
        P[(size_t)blockIdx.y * TB_ + col] = make_float2(mm, ss);
    }
}

// ---------------------------------------------------------------------------
// Fused finish: per column, tree-merge the NVT softmax partials -> lse, then
// dec_out[b][t][v] = bf2f(Lbf[col][v]) - lse,  col = t*32+b
// ---------------------------------------------------------------------------
__global__ __launch_bounds__(256) void subtract_kernel(
    const unsigned short* __restrict__ Lbf, const float2* __restrict__ P,
    float* __restrict__ dout)
{
    __shared__ float2 red[256];
    int col = blockIdx.x;
    int t = col >> 5, b = col & 31;
    int tid = threadIdx.x;

    float2 p = (tid < NVT) ? P[(size_t)tid * TB_ + col]
                           : make_float2(-INFINITY, 0.f);
    red[tid] = p; __syncthreads();
    for (int o = 128; o > 0; o >>= 1) {
        if (tid < o) {
            float2 a = red[tid], c = red[tid + o];
            float mm = fmaxf(a.x, c.x);
            float ss = a.y * __expf(a.x - mm) + c.y * __expf(c.x - mm);
            red[tid] = make_float2(mm, ss);
        }
        __syncthreads();
    }
    float l = red[0].x + logf(red[0].y);

    const u16x8* L = (const u16x8*)(Lbf + (size_t)col * V_);
    float4* o = (float4*)(dout + ((size_t)b * T_ + t) * V_);
    for (int i = tid; i < V_ / 8; i += 256) {
        u16x8 x = L[i];
        float4 v0, v1;
        v0.x = bf2f(x[0]) - l; v0.y = bf2f(x[1]) - l;
        v0.z = bf2f(x[2]) - l; v0.w = bf2f(x[3]) - l;
        v1.x = bf2f(x[4]) - l; v1.y = bf2f(x[5]) - l;
        v1.z = bf2f(x[6]) - l; v1.w = bf2f(x[7]) - l;
        o[i * 2] = v0; o[i * 2 + 1] = v1;
    }
}

// ---------------------------------------------------------------------------
// Fence-free direct-poll grid barrier with s_sleep backoff (round-9 proven).
// ---------------------------------------------------------------------------
__device__ inline void grid_bar4(unsigned* flags, unsigned round)
{
    __syncthreads();
    if (threadIdx.x == 0) {
        asm volatile("s_waitcnt vmcnt(0)" ::: "memory");
        __hip_atomic_store(&flags[(size_t)blockIdx.x * FSTRIDE], round,
                           __ATOMIC_RELAXED, __HIP_MEMORY_SCOPE_AGENT);
    }
    int ok = (threadIdx.x >= NBLK) ? 1 : 0;
    while (true) {
        if (!ok)
            ok = (__hip_atomic_load(&flags[(size_t)threadIdx.x * FSTRIDE],
                                    __ATOMIC_RELAXED, __HIP_MEMORY_SCOPE_AGENT) >= round);
        if (__syncthreads_and(ok)) break;
        __builtin_amdgcn_s_sleep(2);
    }
}

// ---------------------------------------------------------------------------
// Persistent pipelined decode (round-11 structure, best measured).
// ---------------------------------------------------------------------------
__global__ __launch_bounds__(512, 1) void decode_kernel(
    const unsigned short* __restrict__ whh0_bf,   // [3H][H]
    const unsigned short* __restrict__ wih_bf,    // [3][3H][H]
    const unsigned short* __restrict__ whh_bf,    // [3][3H][H]
    const unsigned short* __restrict__ G0,        // [TB][3H] bf16
    const float* __restrict__ b_ih0, const float* __restrict__ b_hh0,
    const float* __restrict__ b_ih,  const float* __restrict__ b_hh,
    const float* __restrict__ enc_hidden,         // [L][B][H] fp32
    unsigned short* __restrict__ hbf,             // [2][L][B][H] bf16
    unsigned short* __restrict__ Hist,            // [TB][H] bf16
    float* __restrict__ hid_out,                  // d_out + B*T*V
    unsigned* __restrict__ flags)
{
    __shared__ float sacc[6][4][16][34];          // rg, kc, row(f), col(b)
    const int tid = threadIdx.x;
    const int wv = tid >> 6, lane = tid & 63;
    const int rlo = lane & 15, klane = (lane >> 4) * 8;
    const int rowoff = (lane >> 4) * 4;
    const int bid = blockIdx.x;

    int layer, f0;
    if (bid < L0BLK) { layer = 0; f0 = bid << 5; }
    else { int r = bid - L0BLK; layer = 1 + (r >> 6); f0 = (r & 63) << 4; }

    const unsigned short* Wih_l = (layer >= 1) ? wih_bf + (size_t)(layer - 1) * N3H * H_ : nullptr;
    const unsigned short* Whh_l = (layer >= 1) ? whh_bf + (size_t)(layer - 1) * N3H * H_ : whh0_bf;

    const int kc = wv & 3, srcgrp = wv >> 2;

    // ---- weight preload into registers ----
    bf16x8 wreg[3][8];
    int rgv[3];
    #pragma unroll
    for (int i = 0; i < 3; ++i) {
        int rg = srcgrp * 3 + i;
        rgv[i] = rg;
        int wrow; const unsigned short* Wm;
        if (layer == 0)      { wrow = (rg >> 1) * H_ + f0 + (rg & 1) * 16; Wm = Whh_l; }
        else if (rg < 3)     { wrow = rg * H_ + f0;        Wm = Wih_l; }
        else                 { wrow = (rg - 3) * H_ + f0;  Wm = Whh_l; }
        const unsigned short* p = Wm + (size_t)(wrow + rlo) * H_ + kc * 256 + klane;
        #pragma unroll
        for (int s = 0; s < 8; ++s) wreg[i][s] = *(const bf16x8*)(p + s * 32);
    }

    // ---- bias + hold-state registers ----
    const float* bihp = (layer == 0) ? b_ih0 : b_ih + (size_t)(layer - 1) * N3H;
    const float* bhhp = (layer == 0) ? b_hh0 : b_hh + (size_t)(layer - 1) * N3H;
    int jj, eb0;
    float hold0, hold1 = 0.f;
    if (layer == 0) {
        jj = f0 + (tid & 31);
        eb0 = tid >> 5;
        hold0 = enc_hidden[(size_t)eb0 * H_ + jj];
        hold1 = enc_hidden[(size_t)(eb0 + 16) * H_ + jj];
    } else {
        jj = f0 + (tid & 15);               // coalesced epilogue stores
        eb0 = tid >> 4;
        hold0 = enc_hidden[(size_t)layer * B_ * H_ + (size_t)eb0 * H_ + jj];
    }
    const float bir = bihp[jj], biz = bihp[H_ + jj], bin_ = bihp[2 * H_ + jj];
    const float bhr = bhhp[jj], bhz = bhhp[H_ + jj], bhn = bhhp[2 * H_ + jj];

    const size_t BH = (size_t)B_ * H_;

    for (int c = 0; c < T_ + L_ - 1; ++c) {
        int t = c - layer;
        if (t >= 0 && t < T_) {
            int pw = t & 1, pr = pw ^ 1;
            const unsigned short* hown  = hbf + ((size_t)pr * L_ + layer) * BH;
            const unsigned short* hprev = (layer > 0)
                ? hbf + ((size_t)pw * L_ + (layer - 1)) * BH : nullptr;

            f32x4 acc[3][2];
            #pragma unroll
            for (int i = 0; i < 3; ++i) {
                acc[i][0] = (f32x4){0.f, 0.f, 0.f, 0.f};
                acc[i][1] = (f32x4){0.f, 0.f, 0.f, 0.f};
            }

            const unsigned short* hsrc = (layer == 0 || srcgrp == 1) ? hown : hprev;
            const unsigned short* hp = hsrc + (size_t)rlo * H_ + kc * 256 + klane;
            #pragma unroll
            for (int s = 0; s < 8; ++s) {
                bf16x8 b0 = ld_h16(hp + s * 32);
                bf16x8 b1 = ld_h16(hp + 16 * H_ + s * 32);
                #pragma unroll
                for (int i = 0; i < 3; ++i) {
                    acc[i][0] = __builtin_amdgcn_mfma_f32_16x16x32_bf16(wreg[i][s], b0, acc[i][0], 0, 0, 0);
                    acc[i][1] = __builtin_amdgcn_mfma_f32_16x16x32_bf16(wreg[i][s], b1, acc[i][1], 0, 0, 0);
                }
            }

            #pragma unroll
            for (int i = 0; i < 3; ++i)
                #pragma unroll
                for (int r = 0; r < 4; ++r) {
                    sacc[rgv[i]][kc][rowoff + r][rlo]      = acc[i][0][r];
                    sacc[rgv[i]][kc][rowoff + r][16 + rlo] = acc[i][1][r];
                }
            __syncthreads();

            if (layer > 0) {
                int f = tid & 15, b = tid >> 4;
                float ir = bir, iz = biz, in_ = bin_;
                float hr = bhr, hz = bhz, hn = bhn;
                #pragma unroll
                for (int k2 = 0; k2 < 4; ++k2) {
                    ir += sacc[0][k2][f][b]; iz += sacc[1][k2][f][b]; in_ += sacc[2][k2][f][b];
                    hr += sacc[3][k2][f][b]; hz += sacc[4][k2][f][b]; hn += sacc[5][k2][f][b];
                }
                float r = 1.f / (1.f + expf(-(ir + hr)));
                float z = 1.f / (1.f + expf(-(iz + hz)));
                float n = tanhf(in_ + r * hn);
                float hnew = (1.f - z) * n + z * hold0;
                hold0 = hnew;
                unsigned short hb16 = f2bf(hnew);
                st_h2(&hbf[((size_t)pw * L_ + layer) * BH + (size_t)b * H_ + jj], hb16);
                if (layer == L_ - 1) Hist[((size_t)t * B_ + b) * H_ + jj] = hb16;
                if (t == T_ - 1) hid_out[(size_t)layer * BH + (size_t)b * H_ + jj] = hnew;
            } else {
                int fi = tid & 31;
                int rghalf = fi >> 4, fr = fi & 15;
                {
                    int b = eb0;
                    const unsigned short* g0p = G0 + ((size_t)t * B_ + b) * N3H;
                    float ir = bf2f(g0p[jj]) + bir;
                    float iz = bf2f(g0p[H_ + jj]) + biz;
                    float in_ = bf2f(g0p[2 * H_ + jj]) + bin_;
                    float hr = bhr, hz = bhz, hn = bhn;
                    #pragma unroll
                    for (int k2 = 0; k2 < 4; ++k2) {
                        hr += sacc[rghalf][k2][fr][b];
                        hz += sacc[2 + rghalf][k2][fr][b];
                        hn += sacc[4 + rghalf][k2][fr][b];
                    }
                    float r = 1.f / (1.f + expf(-(ir + hr)));
                    float z = 1.f / (1.f + expf(-(iz + hz)));
                    float n = tanhf(in_ + r * hn);
                    float hnew = (1.f - z) * n + z * hold0;
                    hold0 = hnew;
                    st_h2(&hbf[((size_t)pw * L_) * BH + (size_t)b * H_ + jj], f2bf(hnew));
                    if (t == T_ - 1) hid_out[(size_t)b * H_ + jj] = hnew;
                }
                {
                    int b = eb0 + 16;
                    const unsigned short* g0p = G0 + ((size_t)t * B_ + b) * N3H;
                    float ir = bf2f(g0p[jj]) + bir;
                    float iz = bf2f(g0p[H_ + jj]) + biz;
                    float in_ = bf2f(g0p[2 * H_ + jj]) + bin_;
                    float hr = bhr, hz = bhz, hn = bhn;
                    #pragma unroll
                    for (int k2 = 0; k2 < 4; ++k2) {
                        hr += sacc[rghalf][k2][fr][b];
                        hz += sacc[2 + rghalf][k2][fr][b];
                        hn += sacc[4 + rghalf][k2][fr][b];
                    }
                    float r = 1.f / (1.f + expf(-(ir + hr)));
                    float z = 1.f / (1.f + expf(-(iz + hz)));
                    float n = tanhf(in_ + r * hn);
                    float hnew = (1.f - z) * n + z * hold1;
                    hold1 = hnew;
                    st_h2(&hbf[((size_t)pw * L_) * BH + (size_t)b * H_ + jj], f2bf(hnew));
                    if (t == T_ - 1) hid_out[(size_t)b * H_ + jj] = hnew;
                }
            }
        }
        grid_bar4(flags, (unsigned)(c + 1));
    }
}

// ---------------------------------------------------------------------------
// Fallback in-place log_softmax + fp32 logits GEMM (workspace-short path)
// ---------------------------------------------------------------------------
__global__ __launch_bounds__(256) void logsoftmax_kernel(float* __restrict__ dout)
{
    __shared__ float red[256];
    float4* x4 = (float4*)(dout + (size_t)blockIdx.x * V_);
    const int N4 = V_ / 4;
    int tid = threadIdx.x;

    float m = -INFINITY, s = 0.f;
    for (int i = tid; i < N4; i += 256) {
        float4 v = x4[i];
        float m4 = fmaxf(fmaxf(v.x, v.y), fmaxf(v.z, v.w));
        if (m4 > m) { s *= expf(m - m4); m = m4; }
        s += expf(v.x - m) + expf(v.y - m) + expf(v.z - m) + expf(v.w - m);
    }
    red[tid] = m; __syncthreads();
    for (int o = 128; o > 0; o >>= 1) {
        if (tid < o) red[tid] = fmaxf(red[tid], red[tid + o]);
        __syncthreads();
    }
    float M = red[0]; __syncthreads();
    red[tid] = s * expf(m - M); __syncthreads();
    for (int o = 128; o > 0; o >>= 1) {
        if (tid < o) red[tid] += red[tid + o];
        __syncthreads();
    }
    float lse = M + logf(red[0]);

    for (int i = tid; i < N4; i += 256) {
        float4 v = x4[i];
        v.x -= lse; v.y -= lse; v.z -= lse; v.w -= lse;
        x4[i] = v;
    }
}

__global__ __launch_bounds__(256) void gemm_logits_f32(
    const unsigned short* __restrict__ A,
    const unsigned short* __restrict__ Bb,
    const float* __restrict__ bias, float* __restrict__ dout)
{
    __shared__ unsigned short Wt[128 * 64];
    __shared__ unsigned short Ht[128 * 64];
    const int tid = threadIdx.x, wv = tid >> 6, lane = tid & 63;
    const int rlo = lane & 15, khw = lane >> 4;
    const int rch = lane >> 3, slot = lane & 7;
    const int rowB = blockIdx.y * 128, colB = blockIdx.x * 128;
    const int wrow0 = rowB + (wv >> 1) * 64;
    const int wcol0 = colB + (wv & 1) * 64;
    const int rA = (wv >> 1) * 64, cA = (wv & 1) * 64;

    f32x4 acc[4][4];
    #pragma unroll
    for (int i = 0; i < 4; ++i)
        #pragma unroll
        for (int j = 0; j < 4; ++j) acc[i][j] = (f32x4){0.f, 0.f, 0.f, 0.f};

    for (int k0 = 0; k0 < H_; k0 += 64) {
        #pragma unroll
        for (int j = 0; j < 4; ++j) {
            int q = wv * 4 + j;
            int row = q * 8 + rch;
            int ss = slot ^ (row & 7);
            gload_lds16(A + (size_t)(rowB + row) * H_ + k0 + ss * 8, Wt + (size_t)q * 512);
            gload_lds16(Bb + (size_t)(colB + row) * H_ + k0 + ss * 8, Ht + (size_t)q * 512);
        }
        __syncthreads();
        const char* WtB = (const char*)Wt;
        const char* HtB = (const char*)Ht;
        #pragma unroll
        for (int kk = 0; kk < 2; ++kk) {
            bf16x8 af[4], bfr[4];
            #pragma unroll
            for (int ri = 0; ri < 4; ++ri) {
                int row = rA + ri * 16 + rlo;
                int ch = (kk * 4 + khw) ^ (row & 7);
                af[ri] = *(const bf16x8*)(WtB + row * 128 + ch * 16);
            }
            #pragma unroll
            for (int ci = 0; ci < 4; ++ci) {
                int col = cA + ci * 16 + rlo;
                int ch = (kk * 4 + khw) ^ (col & 7);
                bfr[ci] = *(const bf16x8*)(HtB + col * 128 + ch * 16);
            }
            #pragma unroll
            for (int ri = 0; ri < 4; ++ri)
                #pragma unroll
                for (int ci = 0; ci < 4; ++ci)
                    acc[ri][ci] = __builtin_amdgcn_mfma_f32_16x16x32_bf16(
                        af[ri], bfr[ci], acc[ri][ci], 0, 0, 0);
        }
        __syncthreads();
    }
    int rowoff = (lane >> 4) * 4;
    #pragma unroll
    for (int ri = 0; ri < 4; ++ri) {
        int row = wrow0 + ri * 16 + rowoff;
        float4 bs = *(const float4*)(bias + row);
        #pragma unroll
        for (int ci = 0; ci < 4; ++ci) {
            int col = wcol0 + ci * 16 + rlo;
            int tt = col >> 5, b = col & 31;
            float4 v;
            v.x = acc[ri][ci][0] + bs.x; v.y = acc[ri][ci][1] + bs.y;
            v.z = acc[ri][ci][2] + bs.z; v.w = acc[ri][ci][3] + bs.w;
            *(float4*)(dout + ((size_t)b * T_ + tt) * V_ + row) = v;
        }
    }
}

// ---------------------------------------------------------------------------
extern "C" void kernel_launch(void* const* d_in, const int* in_sizes, int n_in,
                              void* d_out, int out_size, void* d_ws, size_t ws_size,
                              hipStream_t stream)
{
    (void)in_sizes; (void)n_in; (void)out_size;

    const float* enc_hidden = (const float*)d_in[1];   // [L][B][H]; layer0 = enc_h
    const int*   target     = (const int*)  d_in[2];
    const float* emb        = (const float*)d_in[3];
    const float* w_ih0      = (const float*)d_in[4];   // [3H][2H]
    const float* w_hh0      = (const float*)d_in[5];   // [3H][H]
    const float* b_ih0      = (const float*)d_in[6];
    const float* b_hh0      = (const float*)d_in[7];
    const float* w_ih       = (const float*)d_in[8];   // [3][3H][H]
    const float* w_hh       = (const float*)d_in[9];
    const float* b_ih       = (const float*)d_in[10];
    const float* b_hh       = (const float*)d_in[11];
    const float* out_w      = (const float*)d_in[12];  // [V][H]
    const float* out_b      = (const float*)d_in[13];
    const float* l1_w       = (const float*)d_in[14];
    const float* l1_b       = (const float*)d_in[15];
    const float* l2_w       = (const float*)d_in[16];
    float* out = (float*)d_out;

    // --- workspace carve ---
    char* w = (char*)d_ws;
    auto alloc = [&](size_t bytes) -> char* {
        char* p = w; w += (bytes + 255) & ~(size_t)255; return p;
    };
    unsigned short* whh0_bf = (unsigned short*)alloc((size_t)N3H * H_ * 2);
    unsigned short* wih_bf  = (unsigned short*)alloc((size_t)3 * N3H * H_ * 2);
    unsigned short* whh_bf  = (unsigned short*)alloc((size_t)3 * N3H * H_ * 2);
    unsigned short* Ebf     = (unsigned short*)alloc((size_t)TB_ * H_ * 2);
    unsigned short* G0      = (unsigned short*)alloc((size_t)TB_ * N3H * 2);
    unsigned short* Hist    = (unsigned short*)alloc((size_t)TB_ * H_ * 2);
    unsigned short* hbf     = (unsigned short*)alloc((size_t)2 * L_ * B_ * H_ * 2);
    float*          Cbuf    = (float*)alloc(H_ * 4);
    float*          scores  = (float*)alloc(256);
    float*          wcC     = (float*)alloc(N3H * 4);
    unsigned*       flags   = (unsigned*)alloc((size_t)NBLK * FSTRIDE * 4);
    float2*         Ppart   = (float2*)alloc((size_t)NVT * TB_ * 8);      // 6.4 MB

    size_t used = (size_t)(w - (char*)d_ws);
    unsigned short* wih0f_bf = nullptr;     // full w_ih0 in bf16 [3H][2H]
    if (used + (size_t)N3H * 2 * H_ * 2 + 256 <= ws_size)
        wih0f_bf = (unsigned short*)alloc((size_t)N3H * 2 * H_ * 2);
    used = (size_t)(w - (char*)d_ws);
    unsigned short* outw_bf = nullptr;
    if (used + (size_t)V_ * H_ * 2 + 256 <= ws_size)
        outw_bf = (unsigned short*)alloc((size_t)V_ * H_ * 2);
    used = (size_t)(w - (char*)d_ws);
    unsigned short* Lbf = nullptr;          // bf16 logits [TB][V] = 204.8 MB
    if (used + (size_t)TB_ * V_ * 2 + 256 <= ws_size)
        Lbf = (unsigned short*)alloc((size_t)TB_ * V_ * 2);

    const size_t LBH = (size_t)L_ * B_ * H_;

    hipMemsetAsync(flags, 0, (size_t)NBLK * FSTRIDE * 4, stream);

    // --- one-time precompute ---
    convbf_kernel<<<512, 256, 0, stream>>>(w_hh0, whh0_bf, N3H * H_ / 4);
    convbf_kernel<<<1024, 256, 0, stream>>>(w_ih, wih_bf, 3 * N3H * H_ / 4);
    convbf_kernel<<<1024, 256, 0, stream>>>(w_hh, whh_bf, 3 * N3H * H_ / 4);
    if (wih0f_bf)
        convbf_kernel<<<1024, 256, 0, stream>>>(w_ih0, wih0f_bf, N3H * 2 * H_ / 4);
    if (outw_bf)
        convbf_kernel<<<2048, 256, 0, stream>>>(out_w, outw_bf, V_ * H_ / 4);
    embed_bf_kernel<<<TB_, 256, 0, stream>>>(target, emb, Ebf);
    convbf_kernel<<<128, 256, 0, stream>>>(enc_hidden, hbf + LBH, (int)(LBH / 4));
    attn_pre_kernel<<<1, 256, 0, stream>>>(enc_hidden, l1_w, l1_b, l2_w, Cbuf, scores);
    wcc_kernel<<<N3H / 4, 256, 0, stream>>>(w_ih0, Cbuf, wcC);

    // G0 = W_E @ E (+ wcC bias)
    gemm_staged<<<dim3(TB_ / 128, N3H / 128), 256, 0, stream>>>(
        wih0f_bf, 2 * H_, Ebf, wcC, N3H, 0, G0, nullptr);

    // --- persistent pipelined decode (one launch, 103 grid barriers) ---
    decode_kernel<<<NBLK, 512, 0, stream>>>(
        whh0_bf, wih_bf, whh_bf, G0, b_ih0, b_hh0, b_ih, b_hh,
        enc_hidden, hbf, Hist, out + (size_t)B_ * T_ * V_, flags);

    // --- deferred logits GEMM + fused log_softmax ---
    if (outw_bf && Lbf) {
        gemm_staged<<<dim3(TB_ / 128, V_ / 128), 256, 0, stream>>>(
            outw_bf, H_, Hist, out_b, V_, 2, Lbf, Ppart);
        subtract_kernel<<<TB_, 256, 0, stream>>>(Lbf, Ppart, out);
    } else if (outw_bf) {
        gemm_logits_f32<<<dim3(TB_ / 128, V_ / 128), 256, 0, stream>>>(
            outw_bf, Hist, out_b, out);
        logsoftmax_kernel<<<TB_, 256, 0, stream>>>(out);
    }

    hipMemcpyAsync(out + (size_t)B_ * T_ * V_ + LBH, scores, B_ * 4,
                   hipMemcpyDeviceToDevice, stream);
}